// Round 6
// baseline (766.241 us; speedup 1.0000x reference)
//
#include <hip/hip_runtime.h>
#include <math.h>

#define NN 100000
#define CC 64
#define EPSF 1e-8f
#define LOG_C 4.1588830833596715f
#define SCAN_BS 1024
#define NSB ((NN + SCAN_BS - 1) / SCAN_BS)
#define NB ((NN + 63) / 64)   // 64-row buckets
#define UNBIN_CAP 4096        // max edges per bucket staged in LDS (mean ~1024)

__device__ __forceinline__ float waveSum(float v) {
#pragma unroll
    for (int off = 32; off; off >>= 1) v += __shfl_xor(v, off);
    return v;
}
// reduce across the 16 lanes of a 16-lane group (bits 0..3 of lane id)
__device__ __forceinline__ float redChanSum(float v) {
#pragma unroll
    for (int off = 8; off; off >>= 1) v += __shfl_xor(v, off);
    return v;
}
__device__ __forceinline__ float redChanMax(float v) {
#pragma unroll
    for (int off = 8; off; off >>= 1) v = fmaxf(v, __shfl_xor(v, off));
    return v;
}
// reduce across the 4 groups (bits 4..5 of lane id)
__device__ __forceinline__ float redGrpSum(float v) {
    v += __shfl_xor(v, 16);
    v += __shfl_xor(v, 32);
    return v;
}
__device__ __forceinline__ float clip01(float v) { return fminf(fmaxf(v, 0.f), 1.f); }
__device__ __forceinline__ float sigmoidf(float x) { return 1.f / (1.f + expf(-x)); }

// ---------------- row-wise prologue ----------------

__global__ void k_seed(const float* __restrict__ logits, const float* __restrict__ sf,
                       float* __restrict__ seed, float* __restrict__ mass,
                       float* __restrict__ cert, float* __restrict__ scal) {
    int lane = threadIdx.x & 63;
    int wid = threadIdx.x >> 6;
    float accm = 0.f, accc = 0.f;
    for (int row = blockIdx.x * 4 + wid; row < NN; row += gridDim.x * 4) {
        float l = logits[row * CC + lane];
        float s = fmaxf(l, 0.f);
        seed[row * CC + lane] = s;
        float m = waveSum(s);
        float nrm = s / (m + EPSF);
        float ent = waveSum(-nrm * logf(nrm + EPSF));
        if (lane == 0) {
            mass[row] = m;
            cert[row] = 1.f - ent / LOG_C;
            accm += m;
            accc += sf[row * 2 + 1];
        }
    }
    __shared__ float sm[8];
    if (lane == 0) { sm[wid] = accm; sm[4 + wid] = accc; }
    __syncthreads();
    if (threadIdx.x == 0) {
        atomicAdd(&scal[0], sm[0] + sm[1] + sm[2] + sm[3]);
        atomicAdd(&scal[1], sm[4] + sm[5] + sm[6] + sm[7]);
    }
}

__global__ void k_conf(const float* __restrict__ seed, const float* __restrict__ mass,
                       const float* __restrict__ cert, float* __restrict__ conf,
                       float* __restrict__ sg, float* __restrict__ scal,
                       float* __restrict__ gp) {
    int lane = threadIdx.x & 63;
    int wid = threadIdx.x >> 6;
    float msc = fmaxf(scal[0] * (1.f / NN), EPSF);
    float accgp = 0.f, accconf = 0.f;
    for (int row = blockIdx.x * 4 + wid; row < NN; row += gridDim.x * 4) {
        float m = mass[row], ct = cert[row];
        float cf = clip01(0.5f * ct + 0.5f * tanhf(m / msc));
        accgp += cf * seed[row * CC + lane];
        if (lane == 0) {
            conf[row] = cf;
            sg[row] = sigmoidf(8.f * (cf - 0.55f));
            accconf += cf;
        }
    }
    __shared__ float sgp[256];
    __shared__ float scf[4];
    sgp[threadIdx.x] = accgp;
    if (lane == 0) scf[wid] = accconf;
    __syncthreads();
    if (threadIdx.x < 64)
        atomicAdd(&gp[lane], sgp[lane] + sgp[64 + lane] + sgp[128 + lane] + sgp[192 + lane]);
    if (threadIdx.x == 0) atomicAdd(&scal[2], scf[0] + scf[1] + scf[2] + scf[3]);
}

__global__ void k_finalize(float* __restrict__ scal, float* __restrict__ gp) {
    float sc = fmaxf(scal[2], EPSF);
    gp[threadIdx.x] = gp[threadIdx.x] / sc;
    if (threadIdx.x == 0) {
        scal[3] = fminf(fmaxf(1.f - scal[1] * (1.f / NN), 0.2f), 1.f);
    }
}

// ---------------- CSR build ----------------

__global__ void k_hist(const int* __restrict__ dst, int* __restrict__ count, int E) {
    int i = blockIdx.x * blockDim.x + threadIdx.x;
    int stride = gridDim.x * blockDim.x;
    for (; i < E; i += stride) atomicAdd(&count[dst[i]], 1);
}

__global__ void k_bsum(const int* __restrict__ count, int* __restrict__ bsum) {
    int b = blockIdx.x, t = threadIdx.x;
    int base = b * SCAN_BS + t * 4;
    int s = 0;
#pragma unroll
    for (int k = 0; k < 4; ++k) {
        int i = base + k;
        if (i < NN) s += count[i];
    }
#pragma unroll
    for (int off = 32; off; off >>= 1) s += __shfl_xor(s, off);
    __shared__ int red[4];
    if ((t & 63) == 0) red[t >> 6] = s;
    __syncthreads();
    if (t == 0) bsum[b] = red[0] + red[1] + red[2] + red[3];
}

__global__ void k_boff(const int* __restrict__ bsum, int* __restrict__ boff,
                       int* __restrict__ row_start) {
    int acc = 0;
    for (int i = 0; i < NSB; ++i) { boff[i] = acc; acc += bsum[i]; }
    row_start[NN] = acc;  // == E
}

__global__ void k_scanwrite(const int* __restrict__ count, const int* __restrict__ boff,
                            int* __restrict__ row_start, int* __restrict__ cursor,
                            int* __restrict__ bucket_cursor) {
    int b = blockIdx.x, t = threadIdx.x, lane = t & 63, wid = t >> 6;
    int base = b * SCAN_BS + t * 4;
    int c0 = 0, c1 = 0, c2 = 0, c3 = 0;
    if (base < NN) c0 = count[base];
    if (base + 1 < NN) c1 = count[base + 1];
    if (base + 2 < NN) c2 = count[base + 2];
    if (base + 3 < NN) c3 = count[base + 3];
    int s = c0 + c1 + c2 + c3;
    int incl = s;
#pragma unroll
    for (int off = 1; off < 64; off <<= 1) {
        int o = __shfl_up(incl, off);
        if (lane >= off) incl += o;
    }
    __shared__ int wsum[4];
    if (lane == 63) wsum[wid] = incl;
    __syncthreads();
    int woff = 0;
    for (int i = 0; i < wid; ++i) woff += wsum[i];
    int excl = boff[b] + woff + incl - s;
    if (((base & 63) == 0) && base < NN) bucket_cursor[base >> 6] = excl;
    if (base < NN) { row_start[base] = excl; cursor[base] = excl; excl += c0; }
    if (base + 1 < NN) { row_start[base + 1] = excl; cursor[base + 1] = excl; excl += c1; }
    if (base + 2 < NN) { row_start[base + 2] = excl; cursor[base + 2] = excl; excl += c2; }
    if (base + 3 < NN) { row_start[base + 3] = excl; cursor[base + 3] = excl; excl += c3; }
}

// Phase B: bin edges into 64-row buckets (dense frontier writes, ~no amplification).
// Record: (src | dst_low<<17, w) — src<2^17, dst_low<64.
__global__ void k_binscatter(const int* __restrict__ src, const int* __restrict__ dst,
                             const float* __restrict__ w, int* __restrict__ bucket_cursor,
                             int2* __restrict__ edge_pk, int E) {
    int i = blockIdx.x * blockDim.x + threadIdx.x;
    int stride = gridDim.x * blockDim.x;
    for (; i < E; i += stride) {
        int d = dst[i];
        int b = d >> 6;
        int pos = atomicAdd(&bucket_cursor[b], 1);
        edge_pk[pos] = make_int2(src[i] | ((d & 63) << 17), __float_as_int(w[i]));
    }
}

// Phase C: per-bucket in-place permutation to exact row positions via LDS staging.
// All reads complete (into LDS) before any write — in-place safe.
__global__ __launch_bounds__(256) void k_unbin(const int* __restrict__ row_start,
                                               int* __restrict__ cursor,
                                               int2* __restrict__ edge_pk) {
    __shared__ int2 buf[UNBIN_CAP];
    int b = blockIdx.x;
    int r0 = b << 6;
    int bs = row_start[r0];
    int r1 = min(r0 + 64, NN);
    int be = row_start[r1];
    int sz = min(be - bs, UNBIN_CAP);
    for (int i = threadIdx.x; i < sz; i += 256) buf[i] = edge_pk[bs + i];
    __syncthreads();
    for (int i = threadIdx.x; i < sz; i += 256) {
        int2 t = buf[i];
        int srcv = t.x & 0x1FFFF;
        int d = r0 + ((t.x >> 17) & 63);
        int pos = atomicAdd(&cursor[d], 1);
        edge_pk[pos] = make_int2(srcv, t.y);
    }
}

// ---------------- fused CSR gather + update, one wave per row --------------
// Lane layout: grp = lane>>4 (edge slot), cidx = lane&15 (channel quad).
// MODE 0: ctx=sum w*seed[src]; num=sum (w*sg)*seed[src]; den=sum w*sg;
//         base quality -> bq; fused step-0 update (prop==seed) -> pout.
// MODE 1: num = sum (w*sg[src])*x[src]; fused update -> pout.
// MODE 2: ctx = sum w*x[src]; quality + accept vs bq + blend with seed -> pout.

template <int MODE>
__global__ __launch_bounds__(256) void k_csr(
    const int2* __restrict__ edge_pk, const int* __restrict__ row_start,
    const float* __restrict__ x, const float* __restrict__ sg,
    const float* __restrict__ seed, const float* __restrict__ sf,
    const float* __restrict__ conf, const float* __restrict__ gp,
    const float* __restrict__ scal, float* __restrict__ den,
    float* __restrict__ bq, float* __restrict__ pout) {
    int lane = threadIdx.x & 63;
    int row = blockIdx.x * 4 + (threadIdx.x >> 6);
    if (row >= NN) return;
    int grp = lane >> 4, cidx = lane & 15;
    int rs = row_start[row], re = row_start[row + 1];

    float4 acc = make_float4(0.f, 0.f, 0.f, 0.f);
    float4 accn = make_float4(0.f, 0.f, 0.f, 0.f);
    float accden = 0.f;

    for (int base = rs; base < re; base += 8) {
        int e0 = base + grp;
        int e1 = base + 4 + grp;
        int2 pk0 = make_int2(0, 0), pk1 = make_int2(0, 0);
        if (e0 < re) pk0 = edge_pk[e0];
        if (e1 < re) pk1 = edge_pk[e1];
        float w0 = __int_as_float(pk0.y);
        float w1 = __int_as_float(pk1.y);
        const float4 xv0 = *(const float4*)(x + pk0.x * CC + cidx * 4);
        const float4 xv1 = *(const float4*)(x + pk1.x * CC + cidx * 4);
        if (MODE == 0) {
            float ws0 = w0 * sg[pk0.x];
            float ws1 = w1 * sg[pk1.x];
            acc.x += w0 * xv0.x + w1 * xv1.x;
            acc.y += w0 * xv0.y + w1 * xv1.y;
            acc.z += w0 * xv0.z + w1 * xv1.z;
            acc.w += w0 * xv0.w + w1 * xv1.w;
            accn.x += ws0 * xv0.x + ws1 * xv1.x;
            accn.y += ws0 * xv0.y + ws1 * xv1.y;
            accn.z += ws0 * xv0.z + ws1 * xv1.z;
            accn.w += ws0 * xv0.w + ws1 * xv1.w;
            accden += ws0 + ws1;  // identical across the 16 lanes of a group
        } else if (MODE == 1) {
            float ws0 = w0 * sg[pk0.x];
            float ws1 = w1 * sg[pk1.x];
            acc.x += ws0 * xv0.x + ws1 * xv1.x;
            acc.y += ws0 * xv0.y + ws1 * xv1.y;
            acc.z += ws0 * xv0.z + ws1 * xv1.z;
            acc.w += ws0 * xv0.w + ws1 * xv1.w;
        } else {
            acc.x += w0 * xv0.x + w1 * xv1.x;
            acc.y += w0 * xv0.y + w1 * xv1.y;
            acc.z += w0 * xv0.z + w1 * xv1.z;
            acc.w += w0 * xv0.w + w1 * xv1.w;
        }
    }

    acc.x = redGrpSum(acc.x); acc.y = redGrpSum(acc.y);
    acc.z = redGrpSum(acc.z); acc.w = redGrpSum(acc.w);

    if (MODE == 1) {
        // fused update: f = 0.95*num/den + 0.05*gp; gates; write new prop
        float dn = fmaxf(den[row], EPSF);
        float inv = 1.f / dn;
        const float4 g4 = *(const float4*)(gp + cidx * 4);
        float4 f4;
        f4.x = 0.95f * (acc.x * inv) + 0.05f * g4.x;
        f4.y = 0.95f * (acc.y * inv) + 0.05f * g4.y;
        f4.z = 0.95f * (acc.z * inv) + 0.05f * g4.z;
        f4.w = 0.95f * (acc.w * inv) + 0.05f * g4.w;
        const float4 p4 = *(const float4*)(x + row * CC + cidx * 4);
        const float4 s4 = *(const float4*)(seed + row * CC + cidx * 4);
        float pf = p4.x * f4.x + p4.y * f4.y + p4.z * f4.z + p4.w * f4.w;
        float pp = p4.x * p4.x + p4.y * p4.y + p4.z * p4.z + p4.w * p4.w;
        float ff = f4.x * f4.x + f4.y * f4.y + f4.z * f4.z + f4.w * f4.w;
        float sfv = s4.x * f4.x + s4.y * f4.y + s4.z * f4.z + s4.w * f4.w;
        float ss = s4.x * s4.x + s4.y * s4.y + s4.z * s4.z + s4.w * s4.w;
        pf = redChanSum(pf);
        pp = redChanSum(pp);
        ff = redChanSum(ff);
        sfv = redChanSum(sfv);
        ss = redChanSum(ss);
        float nf = fmaxf(sqrtf(ff), 1e-8f);
        float agree = clip01((pf / (fmaxf(sqrtf(pp), 1e-8f) * nf) + 1.f) * 0.5f);
        float sagree = clip01((sfv / (fmaxf(sqrtf(ss), 1e-8f) * nf) + 1.f) * 0.5f);
        float cf = conf[row];
        float anchor = fminf(fmaxf(0.6f + 0.2f * cf, 0.f), 0.995f);
        float lowdeg = clip01(1.f - sf[row * 2 + 0]);
        float lowcl = clip01(1.f - sf[row * 2 + 1]);
        float rec = sigmoidf(8.f * (0.5f - cf));
        float sel = clip01((1.f - cf) + 0.25f * lowdeg + 0.2f * sagree + 0.2f * lowcl);
        float ug = rec * sel * agree * (1.f - anchor);
        float rsc = 0.15f * scal[3] * ug;
        if (grp == 0) {
            float4 o;
            o.x = fmaxf(anchor * s4.x + (1.f - anchor) * p4.x + rsc * (f4.x - p4.x), 0.f);
            o.y = fmaxf(anchor * s4.y + (1.f - anchor) * p4.y + rsc * (f4.y - p4.y), 0.f);
            o.z = fmaxf(anchor * s4.z + (1.f - anchor) * p4.z + rsc * (f4.z - p4.z), 0.f);
            o.w = fmaxf(anchor * s4.w + (1.f - anchor) * p4.w + rsc * (f4.w - p4.w), 0.f);
            *(float4*)(pout + row * CC + cidx * 4) = o;
        }
        return;
    }

    // quality epilogue (s = seed row for MODE0, prop row for MODE2; c = acc)
    const float4 s4 = *(const float4*)(((MODE == 0) ? seed : x) + row * CC + cidx * 4);
    float dot = s4.x * acc.x + s4.y * acc.y + s4.z * acc.z + s4.w * acc.w;
    float ss = s4.x * s4.x + s4.y * s4.y + s4.z * s4.z + s4.w * s4.w;
    float cc2 = acc.x * acc.x + acc.y * acc.y + acc.z * acc.z + acc.w * acc.w;
    float m = s4.x + s4.y + s4.z + s4.w;
    dot = redChanSum(dot);
    ss = redChanSum(ss);
    cc2 = redChanSum(cc2);
    m = redChanSum(m);
    float cosv = dot / (fmaxf(sqrtf(ss), 1e-8f) * fmaxf(sqrtf(cc2), 1e-8f));
    float lq = clip01((cosv + 1.f) * 0.5f);
    float minv = 1.f / (m + EPSF);
    float p0 = s4.x * minv, p1 = s4.y * minv, p2 = s4.z * minv, p3 = s4.w * minv;
    float m1 = redChanMax(fmaxf(fmaxf(p0, p1), fmaxf(p2, p3)));
    float cnt = (p0 == m1) + (p1 == m1) + (p2 == m1) + (p3 == m1);
    float mlt = -3.4e38f;
    mlt = fmaxf(mlt, (p0 < m1) ? p0 : -3.4e38f);
    mlt = fmaxf(mlt, (p1 < m1) ? p1 : -3.4e38f);
    mlt = fmaxf(mlt, (p2 < m1) ? p2 : -3.4e38f);
    mlt = fmaxf(mlt, (p3 < m1) ? p3 : -3.4e38f);
    cnt = redChanSum(cnt);
    mlt = redChanMax(mlt);
    float m2 = (cnt >= 2.f) ? m1 : mlt;
    float q = 0.7f * lq + 0.2f * (m1 - m2) + 0.1f * sf[row * 2 + 1];

    if (MODE == 0) {
        accn.x = redGrpSum(accn.x); accn.y = redGrpSum(accn.y);
        accn.z = redGrpSum(accn.z); accn.w = redGrpSum(accn.w);
        float dsum = accden;
        dsum += __shfl_xor(dsum, 16);
        dsum += __shfl_xor(dsum, 32);
        float dn = fmaxf(dsum, EPSF);
        float inv = 1.f / dn;
        const float4 g4 = *(const float4*)(gp + cidx * 4);
        float4 f4;
        f4.x = 0.95f * (accn.x * inv) + 0.05f * g4.x;
        f4.y = 0.95f * (accn.y * inv) + 0.05f * g4.y;
        f4.z = 0.95f * (accn.z * inv) + 0.05f * g4.z;
        f4.w = 0.95f * (accn.w * inv) + 0.05f * g4.w;
        // step-0 update: prop == seed, so agree == seed_agree == cos(s,f),
        // and anchor*s + (1-anchor)*s == s
        float sfv = s4.x * f4.x + s4.y * f4.y + s4.z * f4.z + s4.w * f4.w;
        float ff = f4.x * f4.x + f4.y * f4.y + f4.z * f4.z + f4.w * f4.w;
        sfv = redChanSum(sfv);
        ff = redChanSum(ff);
        float nf = fmaxf(sqrtf(ff), 1e-8f);
        float sagree = clip01((sfv / (fmaxf(sqrtf(ss), 1e-8f) * nf) + 1.f) * 0.5f);
        float cf = conf[row];
        float anchor = fminf(fmaxf(0.6f + 0.2f * cf, 0.f), 0.995f);
        float lowdeg = clip01(1.f - sf[row * 2 + 0]);
        float lowcl = clip01(1.f - sf[row * 2 + 1]);
        float rec = sigmoidf(8.f * (0.5f - cf));
        float sel = clip01((1.f - cf) + 0.25f * lowdeg + 0.2f * sagree + 0.2f * lowcl);
        float ug = rec * sel * sagree * (1.f - anchor);
        float rsc = 0.15f * scal[3] * ug;
        if (grp == 0) {
            float4 o;
            o.x = fmaxf(s4.x + rsc * (f4.x - s4.x), 0.f);
            o.y = fmaxf(s4.y + rsc * (f4.y - s4.y), 0.f);
            o.z = fmaxf(s4.z + rsc * (f4.z - s4.z), 0.f);
            o.w = fmaxf(s4.w + rsc * (f4.w - s4.w), 0.f);
            *(float4*)(pout + row * CC + cidx * 4) = o;
        }
        if (lane == 0) {
            den[row] = dsum;
            bq[row] = q;
        }
    } else {  // MODE 2: accept + blend
        float accp = sigmoidf(12.f * (q - bq[row]));
        const float4 sd = *(const float4*)(seed + row * CC + cidx * 4);
        if (grp == 0) {
            float4 o;
            o.x = accp * s4.x + (1.f - accp) * sd.x;
            o.y = accp * s4.y + (1.f - accp) * sd.y;
            o.z = accp * s4.z + (1.f - accp) * sd.z;
            o.w = accp * s4.w + (1.f - accp) * sd.w;
            *(float4*)(pout + row * CC + cidx * 4) = o;
        }
    }
}

// ---------------- launcher ----------------

extern "C" void kernel_launch(void* const* d_in, const int* in_sizes, int n_in,
                              void* d_out, int out_size, void* d_ws, size_t ws_size,
                              hipStream_t stream) {
    const float* logits = (const float*)d_in[0];
    const float* ew = (const float*)d_in[1];
    const float* sf = (const float*)d_in[2];
    const int* esrc = (const int*)d_in[3];
    const int* edst = (const int*)d_in[4];
    float* out = (float*)d_out;
    int E = in_sizes[1];

    float* ws = (float*)d_ws;
    float* seed = ws;                         // N*C
    float* propA = seed + NN * CC;            // N*C
    int2* edge_pk = (int2*)(propA + NN * CC); // E int2
    float* fb = (float*)(edge_pk + E);        // 16B-aligned (offset 16.0M floats)
    float* massA = fb;                        // N
    float* certA = massA + NN;                // N
    float* confA = certA + NN;                // N
    float* sgA = confA + NN;                  // N
    float* denA = sgA + NN;                   // N
    float* bqA = denA + NN;                   // N
    float* scal = bqA + NN;                   // 16 (padded so gp stays 16B-aligned)
    float* gp = scal + 16;                    // 64
    int* count = (int*)(gp + 64);             // N
    int* cursor = count + NN;                 // N
    int* row_start = cursor + NN;             // N+1
    int* bsum = row_start + NN + 1;           // NSB
    int* boff = bsum + NSB;                   // NSB
    int* bucket_cursor = boff + NSB;          // NB
    float* propB = out;                       // d_out doubles as the 2nd prop buffer

    hipMemsetAsync(scal, 0, 16 * sizeof(float), stream);
    hipMemsetAsync(count, 0, NN * sizeof(int), stream);

    const int redBlocks = 1024;
    const int rowBlocks = (NN + 3) / 4;
    const int edgeBlocks = 1024;

    k_seed<<<redBlocks, 256, 0, stream>>>(logits, sf, seed, massA, certA, scal);
    k_conf<<<redBlocks, 256, 0, stream>>>(seed, massA, certA, confA, sgA, scal, gp);
    k_finalize<<<1, 64, 0, stream>>>(scal, gp);

    k_hist<<<edgeBlocks, 256, 0, stream>>>(edst, count, E);
    k_bsum<<<NSB, 256, 0, stream>>>(count, bsum);
    k_boff<<<1, 1, 0, stream>>>(bsum, boff, row_start);
    k_scanwrite<<<NSB, 256, 0, stream>>>(count, boff, row_start, cursor, bucket_cursor);
    k_binscatter<<<edgeBlocks, 256, 0, stream>>>(esrc, edst, ew, bucket_cursor, edge_pk, E);
    k_unbin<<<NB, 256, 0, stream>>>(row_start, cursor, edge_pk);

    // base pass: ctx(seed) quality + den + fused step-0 update (seed -> propA)
    k_csr<0><<<rowBlocks, 256, 0, stream>>>(edge_pk, row_start, seed, sgA, seed, sf,
                                            confA, gp, scal, denA, bqA, propA);
    // steps 1,2: gather + fused update, ping-pong propA <-> propB(d_out)
    k_csr<1><<<rowBlocks, 256, 0, stream>>>(edge_pk, row_start, propA, sgA, seed, sf,
                                            confA, gp, scal, denA, bqA, propB);
    k_csr<1><<<rowBlocks, 256, 0, stream>>>(edge_pk, row_start, propB, sgA, seed, sf,
                                            confA, gp, scal, denA, bqA, propA);
    // final: ctx(prop) quality + accept + blend -> out
    k_csr<2><<<rowBlocks, 256, 0, stream>>>(edge_pk, row_start, propA, sgA, seed, sf,
                                            confA, gp, scal, denA, bqA, out);
}

// Round 7
// 739.976 us; speedup vs baseline: 1.0355x; 1.0355x over previous
//
#include <hip/hip_runtime.h>
#include <math.h>

#define NN 100000
#define CC 64
#define EPSF 1e-8f
#define LOG_C 4.1588830833596715f
#define SCAN_BS 1024
#define NSB ((NN + SCAN_BS - 1) / SCAN_BS)
#define SUPB 10                       // 1024 rows per superbucket
#define NSUP ((NN + 1023) / 1024)     // 98
#define BIN_DEPTH 64
#define BIN_FLUSH 32
#define BIN_BLOCKS 256

__device__ __forceinline__ float waveSum(float v) {
#pragma unroll
    for (int off = 32; off; off >>= 1) v += __shfl_xor(v, off);
    return v;
}
__device__ __forceinline__ float redChanSum(float v) {
#pragma unroll
    for (int off = 8; off; off >>= 1) v += __shfl_xor(v, off);
    return v;
}
__device__ __forceinline__ float redChanMax(float v) {
#pragma unroll
    for (int off = 8; off; off >>= 1) v = fmaxf(v, __shfl_xor(v, off));
    return v;
}
__device__ __forceinline__ float redGrpSum(float v) {
    v += __shfl_xor(v, 16);
    v += __shfl_xor(v, 32);
    return v;
}
__device__ __forceinline__ float clip01(float v) { return fminf(fmaxf(v, 0.f), 1.f); }
__device__ __forceinline__ float sigmoidf(float x) { return 1.f / (1.f + expf(-x)); }

// ---------------- row-wise prologue ----------------

__global__ void k_seed(const float* __restrict__ logits, const float* __restrict__ sf,
                       float* __restrict__ seed, float* __restrict__ mass,
                       float* __restrict__ cert, float* __restrict__ scal) {
    int lane = threadIdx.x & 63;
    int wid = threadIdx.x >> 6;
    float accm = 0.f, accc = 0.f;
    for (int row = blockIdx.x * 4 + wid; row < NN; row += gridDim.x * 4) {
        float l = logits[row * CC + lane];
        float s = fmaxf(l, 0.f);
        seed[row * CC + lane] = s;
        float m = waveSum(s);
        float nrm = s / (m + EPSF);
        float ent = waveSum(-nrm * logf(nrm + EPSF));
        if (lane == 0) {
            mass[row] = m;
            cert[row] = 1.f - ent / LOG_C;
            accm += m;
            accc += sf[row * 2 + 1];
        }
    }
    __shared__ float sm[8];
    if (lane == 0) { sm[wid] = accm; sm[4 + wid] = accc; }
    __syncthreads();
    if (threadIdx.x == 0) {
        atomicAdd(&scal[0], sm[0] + sm[1] + sm[2] + sm[3]);
        atomicAdd(&scal[1], sm[4] + sm[5] + sm[6] + sm[7]);
    }
}

__global__ void k_conf(const float* __restrict__ seed, const float* __restrict__ mass,
                       const float* __restrict__ cert, float* __restrict__ conf,
                       float* __restrict__ sg, float* __restrict__ scal,
                       float* __restrict__ gp) {
    int lane = threadIdx.x & 63;
    int wid = threadIdx.x >> 6;
    float msc = fmaxf(scal[0] * (1.f / NN), EPSF);
    float accgp = 0.f, accconf = 0.f;
    for (int row = blockIdx.x * 4 + wid; row < NN; row += gridDim.x * 4) {
        float m = mass[row], ct = cert[row];
        float cf = clip01(0.5f * ct + 0.5f * tanhf(m / msc));
        accgp += cf * seed[row * CC + lane];
        if (lane == 0) {
            conf[row] = cf;
            sg[row] = sigmoidf(8.f * (cf - 0.55f));
            accconf += cf;
        }
    }
    __shared__ float sgp[256];
    __shared__ float scf[4];
    sgp[threadIdx.x] = accgp;
    if (lane == 0) scf[wid] = accconf;
    __syncthreads();
    if (threadIdx.x < 64)
        atomicAdd(&gp[lane], sgp[lane] + sgp[64 + lane] + sgp[128 + lane] + sgp[192 + lane]);
    if (threadIdx.x == 0) atomicAdd(&scal[2], scf[0] + scf[1] + scf[2] + scf[3]);
}

__global__ void k_finalize(float* __restrict__ scal, float* __restrict__ gp) {
    float sc = fmaxf(scal[2], EPSF);
    gp[threadIdx.x] = gp[threadIdx.x] / sc;
    if (threadIdx.x == 0) {
        scal[3] = fminf(fmaxf(1.f - scal[1] * (1.f / NN), 0.2f), 1.f);
    }
}

// ---------------- CSR build: hist + scan ----------------

__global__ void k_hist(const int* __restrict__ dst, int* __restrict__ count, int E) {
    int i = blockIdx.x * blockDim.x + threadIdx.x;
    int stride = gridDim.x * blockDim.x;
    for (; i < E; i += stride) atomicAdd(&count[dst[i]], 1);
}

__global__ void k_bsum(const int* __restrict__ count, int* __restrict__ bsum) {
    int b = blockIdx.x, t = threadIdx.x;
    int base = b * SCAN_BS + t * 4;
    int s = 0;
#pragma unroll
    for (int k = 0; k < 4; ++k) {
        int i = base + k;
        if (i < NN) s += count[i];
    }
#pragma unroll
    for (int off = 32; off; off >>= 1) s += __shfl_xor(s, off);
    __shared__ int red[4];
    if ((t & 63) == 0) red[t >> 6] = s;
    __syncthreads();
    if (t == 0) bsum[b] = red[0] + red[1] + red[2] + red[3];
}

__global__ void k_boff(const int* __restrict__ bsum, int* __restrict__ boff,
                       int* __restrict__ row_start) {
    int acc = 0;
    for (int i = 0; i < NSB; ++i) { boff[i] = acc; acc += bsum[i]; }
    row_start[NN] = acc;  // == E
}

__global__ void k_scanwrite(const int* __restrict__ count, const int* __restrict__ boff,
                            int* __restrict__ row_start, int* __restrict__ cursor,
                            int* __restrict__ sup_cursor) {
    int b = blockIdx.x, t = threadIdx.x, lane = t & 63, wid = t >> 6;
    int base = b * SCAN_BS + t * 4;
    int c0 = 0, c1 = 0, c2 = 0, c3 = 0;
    if (base < NN) c0 = count[base];
    if (base + 1 < NN) c1 = count[base + 1];
    if (base + 2 < NN) c2 = count[base + 2];
    if (base + 3 < NN) c3 = count[base + 3];
    int s = c0 + c1 + c2 + c3;
    int incl = s;
#pragma unroll
    for (int off = 1; off < 64; off <<= 1) {
        int o = __shfl_up(incl, off);
        if (lane >= off) incl += o;
    }
    __shared__ int wsum[4];
    if (lane == 63) wsum[wid] = incl;
    __syncthreads();
    int woff = 0;
    for (int i = 0; i < wid; ++i) woff += wsum[i];
    int excl = boff[b] + woff + incl - s;
    if (((base & 1023) == 0) && base < NN) sup_cursor[base >> SUPB] = excl;
    if (base < NN) { row_start[base] = excl; cursor[base] = excl; excl += c0; }
    if (base + 1 < NN) { row_start[base + 1] = excl; cursor[base + 1] = excl; excl += c1; }
    if (base + 2 < NN) { row_start[base + 2] = excl; cursor[base + 2] = excl; excl += c2; }
    if (base + 3 < NN) { row_start[base + 3] = excl; cursor[base + 3] = excl; excl += c3; }
}

// ---------------- two-phase LDS-aggregated binning ----------------
// Record: (src | dst_low10<<17, w) — src < 2^17, dst_low < 1024.

// Phase 1: bin into 98 superbuckets of 1024 rows; LDS-buffered, chunked flush.
__global__ __launch_bounds__(256) void k_bin1(const int* __restrict__ src,
                                              const int* __restrict__ dst,
                                              const float* __restrict__ w,
                                              int* __restrict__ sup_cursor,
                                              int2* __restrict__ tmp_pk, int E) {
    __shared__ int2 buf[NSUP][BIN_DEPTH];
    __shared__ int cnt[NSUP];
    int per = (E + BIN_BLOCKS - 1) / BIN_BLOCKS;
    int b0 = blockIdx.x * per;
    int b1 = min(b0 + per, E);
    for (int i = threadIdx.x; i < NSUP; i += 256) cnt[i] = 0;
    __syncthreads();
    int wid = threadIdx.x >> 6, lane = threadIdx.x & 63;
    for (int base = b0; base < b1; base += 256) {
        int e = base + threadIdx.x;
        if (e < b1) {
            int d = dst[e];
            int sb = d >> SUPB;
            int2 rec = make_int2(src[e] | ((d & 1023) << 17), __float_as_int(w[e]));
            int pos = atomicAdd(&cnt[sb], 1);
            if (pos < BIN_DEPTH) {
                buf[sb][pos] = rec;
            } else {  // overflow: direct global write (rare; correct under any skew)
                int gp = atomicAdd(&sup_cursor[sb], 1);
                tmp_pk[gp] = rec;
            }
        }
        __syncthreads();
        for (int sb = wid; sb < NSUP; sb += 4) {
            int c = min(cnt[sb], BIN_DEPTH);
            if (c >= BIN_FLUSH) {
                int gbase;
                if (lane == 0) gbase = atomicAdd(&sup_cursor[sb], c);
                gbase = __shfl(gbase, 0);
                if (lane < c) tmp_pk[gbase + lane] = buf[sb][lane];
                if (lane == 0) cnt[sb] = 0;
            }
        }
        __syncthreads();
    }
    for (int sb = wid; sb < NSUP; sb += 4) {
        int c = min(cnt[sb], BIN_DEPTH);
        if (c > 0) {
            int gbase;
            if (lane == 0) gbase = atomicAdd(&sup_cursor[sb], c);
            gbase = __shfl(gbase, 0);
            if (lane < c) tmp_pk[gbase + lane] = buf[sb][lane];
        }
    }
}

// Phase 2: one block per superbucket; LDS row cursors; writes confined to the
// block's own contiguous CSR slice (single XCD -> L2-merged write-back).
__global__ __launch_bounds__(256) void k_bin2(const int* __restrict__ row_start,
                                              const int2* __restrict__ tmp_pk,
                                              int2* __restrict__ edge_pk) {
    __shared__ int cur[1 << SUPB];
    int b = blockIdx.x;
    int r0 = b << SUPB;
    int r1 = min(r0 + (1 << SUPB), NN);
    for (int i = threadIdx.x; i < r1 - r0; i += 256) cur[i] = row_start[r0 + i];
    __syncthreads();
    int s = row_start[r0], e = row_start[r1];
    for (int i = s + threadIdx.x; i < e; i += 256) {
        int2 t = tmp_pk[i];
        int ld = (t.x >> 17) & 1023;
        int pos = atomicAdd(&cur[ld], 1);
        edge_pk[pos] = make_int2(t.x & 0x1FFFF, t.y);
    }
}

// Fallback (ws too small for tmp): proven direct per-row scatter.
__global__ void k_scatter(const int* __restrict__ src, const int* __restrict__ dst,
                          const float* __restrict__ w, int* __restrict__ cursor,
                          int2* __restrict__ edge_pk, int E) {
    int i = blockIdx.x * blockDim.x + threadIdx.x;
    int stride = gridDim.x * blockDim.x;
    for (; i < E; i += stride) {
        int d = dst[i];
        int pos = atomicAdd(&cursor[d], 1);
        edge_pk[pos] = make_int2(src[i], __float_as_int(w[i]));
    }
}

// ---------------- fused CSR gather + update, one wave per row --------------
// Lane layout: grp = lane>>4 (edge slot), cidx = lane&15 (channel quad).
// MODE 0: ctx=sum w*seed[src]; num=sum (w*sg)*seed[src]; den=sum w*sg;
//         base quality -> bq; fused step-0 update (prop==seed) -> pout.
// MODE 1: num = sum (w*sg[src])*x[src]; fused update -> pout.
// MODE 2: ctx = sum w*x[src]; quality + accept vs bq + blend with seed -> pout.

template <int MODE>
__global__ __launch_bounds__(256) void k_csr(
    const int2* __restrict__ edge_pk, const int* __restrict__ row_start,
    const float* __restrict__ x, const float* __restrict__ sg,
    const float* __restrict__ seed, const float* __restrict__ sf,
    const float* __restrict__ conf, const float* __restrict__ gp,
    const float* __restrict__ scal, float* __restrict__ den,
    float* __restrict__ bq, float* __restrict__ pout) {
    int lane = threadIdx.x & 63;
    int row = blockIdx.x * 4 + (threadIdx.x >> 6);
    if (row >= NN) return;
    int grp = lane >> 4, cidx = lane & 15;
    int rs = row_start[row], re = row_start[row + 1];

    float4 acc = make_float4(0.f, 0.f, 0.f, 0.f);
    float4 accn = make_float4(0.f, 0.f, 0.f, 0.f);
    float accden = 0.f;

    for (int base = rs; base < re; base += 8) {
        int e0 = base + grp;
        int e1 = base + 4 + grp;
        int2 pk0 = make_int2(0, 0), pk1 = make_int2(0, 0);
        if (e0 < re) pk0 = edge_pk[e0];
        if (e1 < re) pk1 = edge_pk[e1];
        float w0 = __int_as_float(pk0.y);
        float w1 = __int_as_float(pk1.y);
        const float4 xv0 = *(const float4*)(x + pk0.x * CC + cidx * 4);
        const float4 xv1 = *(const float4*)(x + pk1.x * CC + cidx * 4);
        if (MODE == 0) {
            float ws0 = w0 * sg[pk0.x];
            float ws1 = w1 * sg[pk1.x];
            acc.x += w0 * xv0.x + w1 * xv1.x;
            acc.y += w0 * xv0.y + w1 * xv1.y;
            acc.z += w0 * xv0.z + w1 * xv1.z;
            acc.w += w0 * xv0.w + w1 * xv1.w;
            accn.x += ws0 * xv0.x + ws1 * xv1.x;
            accn.y += ws0 * xv0.y + ws1 * xv1.y;
            accn.z += ws0 * xv0.z + ws1 * xv1.z;
            accn.w += ws0 * xv0.w + ws1 * xv1.w;
            accden += ws0 + ws1;
        } else if (MODE == 1) {
            float ws0 = w0 * sg[pk0.x];
            float ws1 = w1 * sg[pk1.x];
            acc.x += ws0 * xv0.x + ws1 * xv1.x;
            acc.y += ws0 * xv0.y + ws1 * xv1.y;
            acc.z += ws0 * xv0.z + ws1 * xv1.z;
            acc.w += ws0 * xv0.w + ws1 * xv1.w;
        } else {
            acc.x += w0 * xv0.x + w1 * xv1.x;
            acc.y += w0 * xv0.y + w1 * xv1.y;
            acc.z += w0 * xv0.z + w1 * xv1.z;
            acc.w += w0 * xv0.w + w1 * xv1.w;
        }
    }

    acc.x = redGrpSum(acc.x); acc.y = redGrpSum(acc.y);
    acc.z = redGrpSum(acc.z); acc.w = redGrpSum(acc.w);

    if (MODE == 1) {
        float dn = fmaxf(den[row], EPSF);
        float inv = 1.f / dn;
        const float4 g4 = *(const float4*)(gp + cidx * 4);
        float4 f4;
        f4.x = 0.95f * (acc.x * inv) + 0.05f * g4.x;
        f4.y = 0.95f * (acc.y * inv) + 0.05f * g4.y;
        f4.z = 0.95f * (acc.z * inv) + 0.05f * g4.z;
        f4.w = 0.95f * (acc.w * inv) + 0.05f * g4.w;
        const float4 p4 = *(const float4*)(x + row * CC + cidx * 4);
        const float4 s4 = *(const float4*)(seed + row * CC + cidx * 4);
        float pf = p4.x * f4.x + p4.y * f4.y + p4.z * f4.z + p4.w * f4.w;
        float pp = p4.x * p4.x + p4.y * p4.y + p4.z * p4.z + p4.w * p4.w;
        float ff = f4.x * f4.x + f4.y * f4.y + f4.z * f4.z + f4.w * f4.w;
        float sfv = s4.x * f4.x + s4.y * f4.y + s4.z * f4.z + s4.w * f4.w;
        float ss = s4.x * s4.x + s4.y * s4.y + s4.z * s4.z + s4.w * s4.w;
        pf = redChanSum(pf);
        pp = redChanSum(pp);
        ff = redChanSum(ff);
        sfv = redChanSum(sfv);
        ss = redChanSum(ss);
        float nf = fmaxf(sqrtf(ff), 1e-8f);
        float agree = clip01((pf / (fmaxf(sqrtf(pp), 1e-8f) * nf) + 1.f) * 0.5f);
        float sagree = clip01((sfv / (fmaxf(sqrtf(ss), 1e-8f) * nf) + 1.f) * 0.5f);
        float cf = conf[row];
        float anchor = fminf(fmaxf(0.6f + 0.2f * cf, 0.f), 0.995f);
        float lowdeg = clip01(1.f - sf[row * 2 + 0]);
        float lowcl = clip01(1.f - sf[row * 2 + 1]);
        float rec = sigmoidf(8.f * (0.5f - cf));
        float sel = clip01((1.f - cf) + 0.25f * lowdeg + 0.2f * sagree + 0.2f * lowcl);
        float ug = rec * sel * agree * (1.f - anchor);
        float rsc = 0.15f * scal[3] * ug;
        if (grp == 0) {
            float4 o;
            o.x = fmaxf(anchor * s4.x + (1.f - anchor) * p4.x + rsc * (f4.x - p4.x), 0.f);
            o.y = fmaxf(anchor * s4.y + (1.f - anchor) * p4.y + rsc * (f4.y - p4.y), 0.f);
            o.z = fmaxf(anchor * s4.z + (1.f - anchor) * p4.z + rsc * (f4.z - p4.z), 0.f);
            o.w = fmaxf(anchor * s4.w + (1.f - anchor) * p4.w + rsc * (f4.w - p4.w), 0.f);
            *(float4*)(pout + row * CC + cidx * 4) = o;
        }
        return;
    }

    const float4 s4 = *(const float4*)(((MODE == 0) ? seed : x) + row * CC + cidx * 4);
    float dot = s4.x * acc.x + s4.y * acc.y + s4.z * acc.z + s4.w * acc.w;
    float ss = s4.x * s4.x + s4.y * s4.y + s4.z * s4.z + s4.w * s4.w;
    float cc2 = acc.x * acc.x + acc.y * acc.y + acc.z * acc.z + acc.w * acc.w;
    float m = s4.x + s4.y + s4.z + s4.w;
    dot = redChanSum(dot);
    ss = redChanSum(ss);
    cc2 = redChanSum(cc2);
    m = redChanSum(m);
    float cosv = dot / (fmaxf(sqrtf(ss), 1e-8f) * fmaxf(sqrtf(cc2), 1e-8f));
    float lq = clip01((cosv + 1.f) * 0.5f);
    float minv = 1.f / (m + EPSF);
    float p0 = s4.x * minv, p1 = s4.y * minv, p2 = s4.z * minv, p3 = s4.w * minv;
    float m1 = redChanMax(fmaxf(fmaxf(p0, p1), fmaxf(p2, p3)));
    float cnt = (p0 == m1) + (p1 == m1) + (p2 == m1) + (p3 == m1);
    float mlt = -3.4e38f;
    mlt = fmaxf(mlt, (p0 < m1) ? p0 : -3.4e38f);
    mlt = fmaxf(mlt, (p1 < m1) ? p1 : -3.4e38f);
    mlt = fmaxf(mlt, (p2 < m1) ? p2 : -3.4e38f);
    mlt = fmaxf(mlt, (p3 < m1) ? p3 : -3.4e38f);
    cnt = redChanSum(cnt);
    mlt = redChanMax(mlt);
    float m2 = (cnt >= 2.f) ? m1 : mlt;
    float q = 0.7f * lq + 0.2f * (m1 - m2) + 0.1f * sf[row * 2 + 1];

    if (MODE == 0) {
        accn.x = redGrpSum(accn.x); accn.y = redGrpSum(accn.y);
        accn.z = redGrpSum(accn.z); accn.w = redGrpSum(accn.w);
        float dsum = accden;
        dsum += __shfl_xor(dsum, 16);
        dsum += __shfl_xor(dsum, 32);
        float dn = fmaxf(dsum, EPSF);
        float inv = 1.f / dn;
        const float4 g4 = *(const float4*)(gp + cidx * 4);
        float4 f4;
        f4.x = 0.95f * (accn.x * inv) + 0.05f * g4.x;
        f4.y = 0.95f * (accn.y * inv) + 0.05f * g4.y;
        f4.z = 0.95f * (accn.z * inv) + 0.05f * g4.z;
        f4.w = 0.95f * (accn.w * inv) + 0.05f * g4.w;
        float sfv = s4.x * f4.x + s4.y * f4.y + s4.z * f4.z + s4.w * f4.w;
        float ff = f4.x * f4.x + f4.y * f4.y + f4.z * f4.z + f4.w * f4.w;
        sfv = redChanSum(sfv);
        ff = redChanSum(ff);
        float nf = fmaxf(sqrtf(ff), 1e-8f);
        float sagree = clip01((sfv / (fmaxf(sqrtf(ss), 1e-8f) * nf) + 1.f) * 0.5f);
        float cf = conf[row];
        float anchor = fminf(fmaxf(0.6f + 0.2f * cf, 0.f), 0.995f);
        float lowdeg = clip01(1.f - sf[row * 2 + 0]);
        float lowcl = clip01(1.f - sf[row * 2 + 1]);
        float rec = sigmoidf(8.f * (0.5f - cf));
        float sel = clip01((1.f - cf) + 0.25f * lowdeg + 0.2f * sagree + 0.2f * lowcl);
        float ug = rec * sel * sagree * (1.f - anchor);
        float rsc = 0.15f * scal[3] * ug;
        if (grp == 0) {
            float4 o;
            o.x = fmaxf(s4.x + rsc * (f4.x - s4.x), 0.f);
            o.y = fmaxf(s4.y + rsc * (f4.y - s4.y), 0.f);
            o.z = fmaxf(s4.z + rsc * (f4.z - s4.z), 0.f);
            o.w = fmaxf(s4.w + rsc * (f4.w - s4.w), 0.f);
            *(float4*)(pout + row * CC + cidx * 4) = o;
        }
        if (lane == 0) {
            den[row] = dsum;
            bq[row] = q;
        }
    } else {  // MODE 2
        float accp = sigmoidf(12.f * (q - bq[row]));
        const float4 sd = *(const float4*)(seed + row * CC + cidx * 4);
        if (grp == 0) {
            float4 o;
            o.x = accp * s4.x + (1.f - accp) * sd.x;
            o.y = accp * s4.y + (1.f - accp) * sd.y;
            o.z = accp * s4.z + (1.f - accp) * sd.z;
            o.w = accp * s4.w + (1.f - accp) * sd.w;
            *(float4*)(pout + row * CC + cidx * 4) = o;
        }
    }
}

// ---------------- launcher ----------------

extern "C" void kernel_launch(void* const* d_in, const int* in_sizes, int n_in,
                              void* d_out, int out_size, void* d_ws, size_t ws_size,
                              hipStream_t stream) {
    const float* logits = (const float*)d_in[0];
    const float* ew = (const float*)d_in[1];
    const float* sf = (const float*)d_in[2];
    const int* esrc = (const int*)d_in[3];
    const int* edst = (const int*)d_in[4];
    float* out = (float*)d_out;
    int E = in_sizes[1];

    float* ws = (float*)d_ws;
    float* seed = ws;                         // N*C
    float* propA = seed + NN * CC;            // N*C
    int2* edge_pk = (int2*)(propA + NN * CC); // E int2
    int2* tmp_pk = edge_pk + E;               // E int2 (phase-1 output)
    float* fb = (float*)(tmp_pk + E);
    float* massA = fb;                        // N
    float* certA = massA + NN;                // N
    float* confA = certA + NN;                // N
    float* sgA = confA + NN;                  // N
    float* denA = sgA + NN;                   // N
    float* bqA = denA + NN;                   // N
    float* scal = bqA + NN;                   // 16
    float* gp = scal + 16;                    // 64
    int* count = (int*)(gp + 64);             // N
    int* cursor = count + NN;                 // N
    int* row_start = cursor + NN;             // N+1
    int* bsum = row_start + NN + 1;           // NSB
    int* boff = bsum + NSB;                   // NSB
    int* sup_cursor = boff + NSB;             // NSUP
    float* propB = out;

    size_t need_bytes = (size_t)((char*)(sup_cursor + NSUP) - (char*)ws);
    bool two_phase = ws_size >= need_bytes;

    hipMemsetAsync(scal, 0, 16 * sizeof(float), stream);
    hipMemsetAsync(count, 0, NN * sizeof(int), stream);

    const int redBlocks = 1024;
    const int rowBlocks = (NN + 3) / 4;
    const int edgeBlocks = 1024;

    k_seed<<<redBlocks, 256, 0, stream>>>(logits, sf, seed, massA, certA, scal);
    k_conf<<<redBlocks, 256, 0, stream>>>(seed, massA, certA, confA, sgA, scal, gp);
    k_finalize<<<1, 64, 0, stream>>>(scal, gp);

    k_hist<<<edgeBlocks, 256, 0, stream>>>(edst, count, E);
    k_bsum<<<NSB, 256, 0, stream>>>(count, bsum);
    k_boff<<<1, 1, 0, stream>>>(bsum, boff, row_start);
    k_scanwrite<<<NSB, 256, 0, stream>>>(count, boff, row_start, cursor, sup_cursor);

    if (two_phase) {
        k_bin1<<<BIN_BLOCKS, 256, 0, stream>>>(esrc, edst, ew, sup_cursor, tmp_pk, E);
        k_bin2<<<NSUP, 256, 0, stream>>>(row_start, tmp_pk, edge_pk);
    } else {
        k_scatter<<<edgeBlocks, 256, 0, stream>>>(esrc, edst, ew, cursor, edge_pk, E);
    }

    // base pass: ctx(seed) quality + den + fused step-0 update (seed -> propA)
    k_csr<0><<<rowBlocks, 256, 0, stream>>>(edge_pk, row_start, seed, sgA, seed, sf,
                                            confA, gp, scal, denA, bqA, propA);
    // steps 1,2: gather + fused update, ping-pong propA <-> propB(d_out)
    k_csr<1><<<rowBlocks, 256, 0, stream>>>(edge_pk, row_start, propA, sgA, seed, sf,
                                            confA, gp, scal, denA, bqA, propB);
    k_csr<1><<<rowBlocks, 256, 0, stream>>>(edge_pk, row_start, propB, sgA, seed, sf,
                                            confA, gp, scal, denA, bqA, propA);
    // final: ctx(prop) quality + accept + blend -> out
    k_csr<2><<<rowBlocks, 256, 0, stream>>>(edge_pk, row_start, propA, sgA, seed, sf,
                                            confA, gp, scal, denA, bqA, out);
}

// Round 8
// 608.788 us; speedup vs baseline: 1.2586x; 1.2155x over previous
//
#include <hip/hip_runtime.h>
#include <math.h>

#define NN 100000
#define CC 64
#define EPSF 1e-8f
#define LOG_C 4.1588830833596715f
#define SCAN_BS 1024
#define NSB ((NN + SCAN_BS - 1) / SCAN_BS)

__device__ __forceinline__ float waveSum(float v) {
#pragma unroll
    for (int off = 32; off; off >>= 1) v += __shfl_xor(v, off);
    return v;
}
__device__ __forceinline__ float redChanSum(float v) {
#pragma unroll
    for (int off = 8; off; off >>= 1) v += __shfl_xor(v, off);
    return v;
}
__device__ __forceinline__ float redChanMax(float v) {
#pragma unroll
    for (int off = 8; off; off >>= 1) v = fmaxf(v, __shfl_xor(v, off));
    return v;
}
__device__ __forceinline__ float redGrpSum(float v) {
    v += __shfl_xor(v, 16);
    v += __shfl_xor(v, 32);
    return v;
}
__device__ __forceinline__ float clip01(float v) { return fminf(fmaxf(v, 0.f), 1.f); }
__device__ __forceinline__ float sigmoidf(float x) { return 1.f / (1.f + expf(-x)); }

// ---------------- row-wise prologue ----------------

__global__ void k_seed(const float* __restrict__ logits, const float* __restrict__ sf,
                       float* __restrict__ seed, float* __restrict__ mass,
                       float* __restrict__ cert, float* __restrict__ scal) {
    int lane = threadIdx.x & 63;
    int wid = threadIdx.x >> 6;
    float accm = 0.f, accc = 0.f;
    for (int row = blockIdx.x * 4 + wid; row < NN; row += gridDim.x * 4) {
        float l = logits[row * CC + lane];
        float s = fmaxf(l, 0.f);
        seed[row * CC + lane] = s;
        float m = waveSum(s);
        float nrm = s / (m + EPSF);
        float ent = waveSum(-nrm * logf(nrm + EPSF));
        if (lane == 0) {
            mass[row] = m;
            cert[row] = 1.f - ent / LOG_C;
            accm += m;
            accc += sf[row * 2 + 1];
        }
    }
    __shared__ float sm[8];
    if (lane == 0) { sm[wid] = accm; sm[4 + wid] = accc; }
    __syncthreads();
    if (threadIdx.x == 0) {
        atomicAdd(&scal[0], sm[0] + sm[1] + sm[2] + sm[3]);
        atomicAdd(&scal[1], sm[4] + sm[5] + sm[6] + sm[7]);
    }
}

__global__ void k_conf(const float* __restrict__ seed, const float* __restrict__ mass,
                       const float* __restrict__ cert, float* __restrict__ conf,
                       float* __restrict__ sg, float* __restrict__ scal,
                       float* __restrict__ gp) {
    int lane = threadIdx.x & 63;
    int wid = threadIdx.x >> 6;
    float msc = fmaxf(scal[0] * (1.f / NN), EPSF);
    float accgp = 0.f, accconf = 0.f;
    for (int row = blockIdx.x * 4 + wid; row < NN; row += gridDim.x * 4) {
        float m = mass[row], ct = cert[row];
        float cf = clip01(0.5f * ct + 0.5f * tanhf(m / msc));
        accgp += cf * seed[row * CC + lane];
        if (lane == 0) {
            conf[row] = cf;
            sg[row] = sigmoidf(8.f * (cf - 0.55f));
            accconf += cf;
        }
    }
    __shared__ float sgp[256];
    __shared__ float scf[4];
    sgp[threadIdx.x] = accgp;
    if (lane == 0) scf[wid] = accconf;
    __syncthreads();
    if (threadIdx.x < 64)
        atomicAdd(&gp[lane], sgp[lane] + sgp[64 + lane] + sgp[128 + lane] + sgp[192 + lane]);
    if (threadIdx.x == 0) atomicAdd(&scal[2], scf[0] + scf[1] + scf[2] + scf[3]);
}

__global__ void k_finalize(float* __restrict__ scal, float* __restrict__ gp) {
    float sc = fmaxf(scal[2], EPSF);
    gp[threadIdx.x] = gp[threadIdx.x] / sc;
    if (threadIdx.x == 0) {
        scal[3] = fminf(fmaxf(1.f - scal[1] * (1.f / NN), 0.2f), 1.f);
    }
}

// ---------------- CSR build: hist + scan + direct scatter ----------------

__global__ void k_hist(const int* __restrict__ dst, int* __restrict__ count, int E) {
    int i = blockIdx.x * blockDim.x + threadIdx.x;
    int stride = gridDim.x * blockDim.x;
    for (; i < E; i += stride) atomicAdd(&count[dst[i]], 1);
}

__global__ void k_bsum(const int* __restrict__ count, int* __restrict__ bsum) {
    int b = blockIdx.x, t = threadIdx.x;
    int base = b * SCAN_BS + t * 4;
    int s = 0;
#pragma unroll
    for (int k = 0; k < 4; ++k) {
        int i = base + k;
        if (i < NN) s += count[i];
    }
#pragma unroll
    for (int off = 32; off; off >>= 1) s += __shfl_xor(s, off);
    __shared__ int red[4];
    if ((t & 63) == 0) red[t >> 6] = s;
    __syncthreads();
    if (t == 0) bsum[b] = red[0] + red[1] + red[2] + red[3];
}

__global__ void k_boff(const int* __restrict__ bsum, int* __restrict__ boff,
                       int* __restrict__ row_start) {
    int acc = 0;
    for (int i = 0; i < NSB; ++i) { boff[i] = acc; acc += bsum[i]; }
    row_start[NN] = acc;  // == E
}

__global__ void k_scanwrite(const int* __restrict__ count, const int* __restrict__ boff,
                            int* __restrict__ row_start, int* __restrict__ cursor) {
    int b = blockIdx.x, t = threadIdx.x, lane = t & 63, wid = t >> 6;
    int base = b * SCAN_BS + t * 4;
    int c0 = 0, c1 = 0, c2 = 0, c3 = 0;
    if (base < NN) c0 = count[base];
    if (base + 1 < NN) c1 = count[base + 1];
    if (base + 2 < NN) c2 = count[base + 2];
    if (base + 3 < NN) c3 = count[base + 3];
    int s = c0 + c1 + c2 + c3;
    int incl = s;
#pragma unroll
    for (int off = 1; off < 64; off <<= 1) {
        int o = __shfl_up(incl, off);
        if (lane >= off) incl += o;
    }
    __shared__ int wsum[4];
    if (lane == 63) wsum[wid] = incl;
    __syncthreads();
    int woff = 0;
    for (int i = 0; i < wid; ++i) woff += wsum[i];
    int excl = boff[b] + woff + incl - s;
    if (base < NN) { row_start[base] = excl; cursor[base] = excl; excl += c0; }
    if (base + 1 < NN) { row_start[base + 1] = excl; cursor[base + 1] = excl; excl += c1; }
    if (base + 2 < NN) { row_start[base + 2] = excl; cursor[base + 2] = excl; excl += c2; }
    if (base + 3 < NN) { row_start[base + 3] = excl; cursor[base + 3] = excl; excl += c3; }
}

// Direct per-row scatter (measured 140 µs: bound by random 64B line write-backs;
// beats both global-frontier binning (239) and LDS-aggregated binning (255)).
__global__ void k_scatter(const int* __restrict__ src, const int* __restrict__ dst,
                          const float* __restrict__ w, int* __restrict__ cursor,
                          int2* __restrict__ edge_pk, int E) {
    int i = blockIdx.x * blockDim.x + threadIdx.x;
    int stride = gridDim.x * blockDim.x;
    for (; i < E; i += stride) {
        int d = dst[i];
        int pos = atomicAdd(&cursor[d], 1);
        edge_pk[pos] = make_int2(src[i], __float_as_int(w[i]));
    }
}

// ---------------- fused CSR gather + update, one wave per row --------------
// Lane layout: grp = lane>>4 (edge slot), cidx = lane&15 (channel quad).
// MODE 0: ctx=sum w*seed[src]; num=sum (w*sg)*seed[src]; den=sum w*sg;
//         base quality -> bq; fused step-0 update (prop==seed) -> pout.
// MODE 1: num = sum (w*sg[src])*x[src]; fused update -> pout.
// MODE 2: ctx = sum w*x[src]; quality + accept vs bq + blend with seed -> pout.

template <int MODE>
__global__ __launch_bounds__(256) void k_csr(
    const int2* __restrict__ edge_pk, const int* __restrict__ row_start,
    const float* __restrict__ x, const float* __restrict__ sg,
    const float* __restrict__ seed, const float* __restrict__ sf,
    const float* __restrict__ conf, const float* __restrict__ gp,
    const float* __restrict__ scal, float* __restrict__ den,
    float* __restrict__ bq, float* __restrict__ pout) {
    int lane = threadIdx.x & 63;
    int row = blockIdx.x * 4 + (threadIdx.x >> 6);
    if (row >= NN) return;
    int grp = lane >> 4, cidx = lane & 15;
    int rs = row_start[row], re = row_start[row + 1];

    float4 acc = make_float4(0.f, 0.f, 0.f, 0.f);
    float4 accn = make_float4(0.f, 0.f, 0.f, 0.f);
    float accden = 0.f;

    for (int base = rs; base < re; base += 8) {
        int e0 = base + grp;
        int e1 = base + 4 + grp;
        int2 pk0 = make_int2(0, 0), pk1 = make_int2(0, 0);
        if (e0 < re) pk0 = edge_pk[e0];
        if (e1 < re) pk1 = edge_pk[e1];
        float w0 = __int_as_float(pk0.y);
        float w1 = __int_as_float(pk1.y);
        const float4 xv0 = *(const float4*)(x + pk0.x * CC + cidx * 4);
        const float4 xv1 = *(const float4*)(x + pk1.x * CC + cidx * 4);
        if (MODE == 0) {
            float ws0 = w0 * sg[pk0.x];
            float ws1 = w1 * sg[pk1.x];
            acc.x += w0 * xv0.x + w1 * xv1.x;
            acc.y += w0 * xv0.y + w1 * xv1.y;
            acc.z += w0 * xv0.z + w1 * xv1.z;
            acc.w += w0 * xv0.w + w1 * xv1.w;
            accn.x += ws0 * xv0.x + ws1 * xv1.x;
            accn.y += ws0 * xv0.y + ws1 * xv1.y;
            accn.z += ws0 * xv0.z + ws1 * xv1.z;
            accn.w += ws0 * xv0.w + ws1 * xv1.w;
            accden += ws0 + ws1;
        } else if (MODE == 1) {
            float ws0 = w0 * sg[pk0.x];
            float ws1 = w1 * sg[pk1.x];
            acc.x += ws0 * xv0.x + ws1 * xv1.x;
            acc.y += ws0 * xv0.y + ws1 * xv1.y;
            acc.z += ws0 * xv0.z + ws1 * xv1.z;
            acc.w += ws0 * xv0.w + ws1 * xv1.w;
        } else {
            acc.x += w0 * xv0.x + w1 * xv1.x;
            acc.y += w0 * xv0.y + w1 * xv1.y;
            acc.z += w0 * xv0.z + w1 * xv1.z;
            acc.w += w0 * xv0.w + w1 * xv1.w;
        }
    }

    acc.x = redGrpSum(acc.x); acc.y = redGrpSum(acc.y);
    acc.z = redGrpSum(acc.z); acc.w = redGrpSum(acc.w);

    if (MODE == 1) {
        float dn = fmaxf(den[row], EPSF);
        float inv = 1.f / dn;
        const float4 g4 = *(const float4*)(gp + cidx * 4);
        float4 f4;
        f4.x = 0.95f * (acc.x * inv) + 0.05f * g4.x;
        f4.y = 0.95f * (acc.y * inv) + 0.05f * g4.y;
        f4.z = 0.95f * (acc.z * inv) + 0.05f * g4.z;
        f4.w = 0.95f * (acc.w * inv) + 0.05f * g4.w;
        const float4 p4 = *(const float4*)(x + row * CC + cidx * 4);
        const float4 s4 = *(const float4*)(seed + row * CC + cidx * 4);
        float pf = p4.x * f4.x + p4.y * f4.y + p4.z * f4.z + p4.w * f4.w;
        float pp = p4.x * p4.x + p4.y * p4.y + p4.z * p4.z + p4.w * p4.w;
        float ff = f4.x * f4.x + f4.y * f4.y + f4.z * f4.z + f4.w * f4.w;
        float sfv = s4.x * f4.x + s4.y * f4.y + s4.z * f4.z + s4.w * f4.w;
        float ss = s4.x * s4.x + s4.y * s4.y + s4.z * s4.z + s4.w * s4.w;
        pf = redChanSum(pf);
        pp = redChanSum(pp);
        ff = redChanSum(ff);
        sfv = redChanSum(sfv);
        ss = redChanSum(ss);
        float nf = fmaxf(sqrtf(ff), 1e-8f);
        float agree = clip01((pf / (fmaxf(sqrtf(pp), 1e-8f) * nf) + 1.f) * 0.5f);
        float sagree = clip01((sfv / (fmaxf(sqrtf(ss), 1e-8f) * nf) + 1.f) * 0.5f);
        float cf = conf[row];
        float anchor = fminf(fmaxf(0.6f + 0.2f * cf, 0.f), 0.995f);
        float lowdeg = clip01(1.f - sf[row * 2 + 0]);
        float lowcl = clip01(1.f - sf[row * 2 + 1]);
        float rec = sigmoidf(8.f * (0.5f - cf));
        float sel = clip01((1.f - cf) + 0.25f * lowdeg + 0.2f * sagree + 0.2f * lowcl);
        float ug = rec * sel * agree * (1.f - anchor);
        float rsc = 0.15f * scal[3] * ug;
        if (grp == 0) {
            float4 o;
            o.x = fmaxf(anchor * s4.x + (1.f - anchor) * p4.x + rsc * (f4.x - p4.x), 0.f);
            o.y = fmaxf(anchor * s4.y + (1.f - anchor) * p4.y + rsc * (f4.y - p4.y), 0.f);
            o.z = fmaxf(anchor * s4.z + (1.f - anchor) * p4.z + rsc * (f4.z - p4.z), 0.f);
            o.w = fmaxf(anchor * s4.w + (1.f - anchor) * p4.w + rsc * (f4.w - p4.w), 0.f);
            *(float4*)(pout + row * CC + cidx * 4) = o;
        }
        return;
    }

    const float4 s4 = *(const float4*)(((MODE == 0) ? seed : x) + row * CC + cidx * 4);
    float dot = s4.x * acc.x + s4.y * acc.y + s4.z * acc.z + s4.w * acc.w;
    float ss = s4.x * s4.x + s4.y * s4.y + s4.z * s4.z + s4.w * s4.w;
    float cc2 = acc.x * acc.x + acc.y * acc.y + acc.z * acc.z + acc.w * acc.w;
    float m = s4.x + s4.y + s4.z + s4.w;
    dot = redChanSum(dot);
    ss = redChanSum(ss);
    cc2 = redChanSum(cc2);
    m = redChanSum(m);
    float cosv = dot / (fmaxf(sqrtf(ss), 1e-8f) * fmaxf(sqrtf(cc2), 1e-8f));
    float lq = clip01((cosv + 1.f) * 0.5f);
    float minv = 1.f / (m + EPSF);
    float p0 = s4.x * minv, p1 = s4.y * minv, p2 = s4.z * minv, p3 = s4.w * minv;
    float m1 = redChanMax(fmaxf(fmaxf(p0, p1), fmaxf(p2, p3)));
    float cnt = (p0 == m1) + (p1 == m1) + (p2 == m1) + (p3 == m1);
    float mlt = -3.4e38f;
    mlt = fmaxf(mlt, (p0 < m1) ? p0 : -3.4e38f);
    mlt = fmaxf(mlt, (p1 < m1) ? p1 : -3.4e38f);
    mlt = fmaxf(mlt, (p2 < m1) ? p2 : -3.4e38f);
    mlt = fmaxf(mlt, (p3 < m1) ? p3 : -3.4e38f);
    cnt = redChanSum(cnt);
    mlt = redChanMax(mlt);
    float m2 = (cnt >= 2.f) ? m1 : mlt;
    float q = 0.7f * lq + 0.2f * (m1 - m2) + 0.1f * sf[row * 2 + 1];

    if (MODE == 0) {
        accn.x = redGrpSum(accn.x); accn.y = redGrpSum(accn.y);
        accn.z = redGrpSum(accn.z); accn.w = redGrpSum(accn.w);
        float dsum = accden;
        dsum += __shfl_xor(dsum, 16);
        dsum += __shfl_xor(dsum, 32);
        float dn = fmaxf(dsum, EPSF);
        float inv = 1.f / dn;
        const float4 g4 = *(const float4*)(gp + cidx * 4);
        float4 f4;
        f4.x = 0.95f * (accn.x * inv) + 0.05f * g4.x;
        f4.y = 0.95f * (accn.y * inv) + 0.05f * g4.y;
        f4.z = 0.95f * (accn.z * inv) + 0.05f * g4.z;
        f4.w = 0.95f * (accn.w * inv) + 0.05f * g4.w;
        float sfv = s4.x * f4.x + s4.y * f4.y + s4.z * f4.z + s4.w * f4.w;
        float ff = f4.x * f4.x + f4.y * f4.y + f4.z * f4.z + f4.w * f4.w;
        sfv = redChanSum(sfv);
        ff = redChanSum(ff);
        float nf = fmaxf(sqrtf(ff), 1e-8f);
        float sagree = clip01((sfv / (fmaxf(sqrtf(ss), 1e-8f) * nf) + 1.f) * 0.5f);
        float cf = conf[row];
        float anchor = fminf(fmaxf(0.6f + 0.2f * cf, 0.f), 0.995f);
        float lowdeg = clip01(1.f - sf[row * 2 + 0]);
        float lowcl = clip01(1.f - sf[row * 2 + 1]);
        float rec = sigmoidf(8.f * (0.5f - cf));
        float sel = clip01((1.f - cf) + 0.25f * lowdeg + 0.2f * sagree + 0.2f * lowcl);
        float ug = rec * sel * sagree * (1.f - anchor);
        float rsc = 0.15f * scal[3] * ug;
        if (grp == 0) {
            float4 o;
            o.x = fmaxf(s4.x + rsc * (f4.x - s4.x), 0.f);
            o.y = fmaxf(s4.y + rsc * (f4.y - s4.y), 0.f);
            o.z = fmaxf(s4.z + rsc * (f4.z - s4.z), 0.f);
            o.w = fmaxf(s4.w + rsc * (f4.w - s4.w), 0.f);
            *(float4*)(pout + row * CC + cidx * 4) = o;
        }
        if (lane == 0) {
            den[row] = dsum;
            bq[row] = q;
        }
    } else {  // MODE 2
        float accp = sigmoidf(12.f * (q - bq[row]));
        const float4 sd = *(const float4*)(seed + row * CC + cidx * 4);
        if (grp == 0) {
            float4 o;
            o.x = accp * s4.x + (1.f - accp) * sd.x;
            o.y = accp * s4.y + (1.f - accp) * sd.y;
            o.z = accp * s4.z + (1.f - accp) * sd.z;
            o.w = accp * s4.w + (1.f - accp) * sd.w;
            *(float4*)(pout + row * CC + cidx * 4) = o;
        }
    }
}

// ---------------- launcher ----------------

extern "C" void kernel_launch(void* const* d_in, const int* in_sizes, int n_in,
                              void* d_out, int out_size, void* d_ws, size_t ws_size,
                              hipStream_t stream) {
    const float* logits = (const float*)d_in[0];
    const float* ew = (const float*)d_in[1];
    const float* sf = (const float*)d_in[2];
    const int* esrc = (const int*)d_in[3];
    const int* edst = (const int*)d_in[4];
    float* out = (float*)d_out;
    int E = in_sizes[1];

    float* ws = (float*)d_ws;
    float* seed = ws;                         // N*C
    float* propA = seed + NN * CC;            // N*C
    int2* edge_pk = (int2*)(propA + NN * CC); // E int2
    float* fb = (float*)(edge_pk + E);
    float* massA = fb;                        // N
    float* certA = massA + NN;                // N
    float* confA = certA + NN;                // N
    float* sgA = confA + NN;                  // N
    float* denA = sgA + NN;                   // N
    float* bqA = denA + NN;                   // N
    float* scal = bqA + NN;                   // 16
    float* gp = scal + 16;                    // 64
    int* count = (int*)(gp + 64);             // N
    int* cursor = count + NN;                 // N
    int* row_start = cursor + NN;             // N+1
    int* bsum = row_start + NN + 1;           // NSB
    int* boff = bsum + NSB;                   // NSB
    float* propB = out;                       // d_out doubles as 2nd prop buffer

    hipMemsetAsync(scal, 0, 16 * sizeof(float), stream);
    hipMemsetAsync(count, 0, NN * sizeof(int), stream);

    const int redBlocks = 1024;
    const int rowBlocks = (NN + 3) / 4;
    const int edgeBlocks = 1024;

    k_seed<<<redBlocks, 256, 0, stream>>>(logits, sf, seed, massA, certA, scal);
    k_conf<<<redBlocks, 256, 0, stream>>>(seed, massA, certA, confA, sgA, scal, gp);
    k_finalize<<<1, 64, 0, stream>>>(scal, gp);

    k_hist<<<edgeBlocks, 256, 0, stream>>>(edst, count, E);
    k_bsum<<<NSB, 256, 0, stream>>>(count, bsum);
    k_boff<<<1, 1, 0, stream>>>(bsum, boff, row_start);
    k_scanwrite<<<NSB, 256, 0, stream>>>(count, boff, row_start, cursor);
    k_scatter<<<edgeBlocks, 256, 0, stream>>>(esrc, edst, ew, cursor, edge_pk, E);

    // base pass: ctx(seed) quality + den + fused step-0 update (seed -> propA)
    k_csr<0><<<rowBlocks, 256, 0, stream>>>(edge_pk, row_start, seed, sgA, seed, sf,
                                            confA, gp, scal, denA, bqA, propA);
    // steps 1,2: gather + fused update, ping-pong propA <-> propB(d_out)
    k_csr<1><<<rowBlocks, 256, 0, stream>>>(edge_pk, row_start, propA, sgA, seed, sf,
                                            confA, gp, scal, denA, bqA, propB);
    k_csr<1><<<rowBlocks, 256, 0, stream>>>(edge_pk, row_start, propB, sgA, seed, sf,
                                            confA, gp, scal, denA, bqA, propA);
    // final: ctx(prop) quality + accept + blend -> out
    k_csr<2><<<rowBlocks, 256, 0, stream>>>(edge_pk, row_start, propA, sgA, seed, sf,
                                            confA, gp, scal, denA, bqA, out);
}

// Round 10
// 582.206 us; speedup vs baseline: 1.3161x; 1.0457x over previous
//
#include <hip/hip_runtime.h>
#include <math.h>

#define NN 100000
#define CC 64
#define EPSF 1e-8f
#define LOG_C 4.1588830833596715f
#define SCAN_BS 1024
#define NSB ((NN + SCAN_BS - 1) / SCAN_BS)

typedef unsigned short ushortT;
typedef unsigned int uintT;

__device__ __forceinline__ float waveSum(float v) {
#pragma unroll
    for (int off = 32; off; off >>= 1) v += __shfl_xor(v, off);
    return v;
}
// reduce across the 8 channel-lanes (bits 0..2)
__device__ __forceinline__ float redCSum(float v) {
    v += __shfl_xor(v, 1); v += __shfl_xor(v, 2); v += __shfl_xor(v, 4);
    return v;
}
__device__ __forceinline__ float redCMax(float v) {
    v = fmaxf(v, __shfl_xor(v, 1)); v = fmaxf(v, __shfl_xor(v, 2)); v = fmaxf(v, __shfl_xor(v, 4));
    return v;
}
// reduce across the 8 edge-groups (bits 3..5)
__device__ __forceinline__ float redGSum(float v) {
    v += __shfl_xor(v, 8); v += __shfl_xor(v, 16); v += __shfl_xor(v, 32);
    return v;
}
__device__ __forceinline__ float clip01(float v) { return fminf(fmaxf(v, 0.f), 1.f); }
__device__ __forceinline__ float sigmoidf(float x) { return 1.f / (1.f + expf(-x)); }

__device__ __forceinline__ void unpack8(const uint4 v, float* x) {
    x[0] = __uint_as_float(v.x << 16); x[1] = __uint_as_float(v.x & 0xFFFF0000u);
    x[2] = __uint_as_float(v.y << 16); x[3] = __uint_as_float(v.y & 0xFFFF0000u);
    x[4] = __uint_as_float(v.z << 16); x[5] = __uint_as_float(v.z & 0xFFFF0000u);
    x[6] = __uint_as_float(v.w << 16); x[7] = __uint_as_float(v.w & 0xFFFF0000u);
}
__device__ __forceinline__ uintT f2bf(float f) {  // RNE round to bf16 (low 16 bits)
    uintT u = __float_as_uint(f);
    return (u + 0x7FFFu + ((u >> 16) & 1u)) >> 16;
}
__device__ __forceinline__ uint4 pack8(const float* x) {
    uint4 o;
    o.x = f2bf(x[0]) | (f2bf(x[1]) << 16);
    o.y = f2bf(x[2]) | (f2bf(x[3]) << 16);
    o.z = f2bf(x[4]) | (f2bf(x[5]) << 16);
    o.w = f2bf(x[6]) | (f2bf(x[7]) << 16);
    return o;
}

// ---------------- row-wise prologue ----------------

__global__ void k_seed(const float* __restrict__ logits, const float* __restrict__ sf,
                       float* __restrict__ seedF, ushortT* __restrict__ seedH,
                       float* __restrict__ mass, float* __restrict__ cert,
                       float* __restrict__ scal) {
    int lane = threadIdx.x & 63;
    int wid = threadIdx.x >> 6;
    float accm = 0.f, accc = 0.f;
    for (int row = blockIdx.x * 4 + wid; row < NN; row += gridDim.x * 4) {
        float l = logits[row * CC + lane];
        float s = fmaxf(l, 0.f);
        seedF[row * CC + lane] = s;
        seedH[row * CC + lane] = (ushortT)f2bf(s);
        float m = waveSum(s);
        float nrm = s / (m + EPSF);
        float ent = waveSum(-nrm * logf(nrm + EPSF));
        if (lane == 0) {
            mass[row] = m;
            cert[row] = 1.f - ent / LOG_C;
            accm += m;
            accc += sf[row * 2 + 1];
        }
    }
    __shared__ float sm[8];
    if (lane == 0) { sm[wid] = accm; sm[4 + wid] = accc; }
    __syncthreads();
    if (threadIdx.x == 0) {
        atomicAdd(&scal[0], sm[0] + sm[1] + sm[2] + sm[3]);
        atomicAdd(&scal[1], sm[4] + sm[5] + sm[6] + sm[7]);
    }
}

__global__ void k_conf(const float* __restrict__ seedF, const float* __restrict__ mass,
                       const float* __restrict__ cert, float* __restrict__ conf,
                       float* __restrict__ sg, float* __restrict__ scal,
                       float* __restrict__ gp) {
    int lane = threadIdx.x & 63;
    int wid = threadIdx.x >> 6;
    float msc = fmaxf(scal[0] * (1.f / NN), EPSF);
    float accgp = 0.f, accconf = 0.f;
    for (int row = blockIdx.x * 4 + wid; row < NN; row += gridDim.x * 4) {
        float m = mass[row], ct = cert[row];
        float cf = clip01(0.5f * ct + 0.5f * tanhf(m / msc));
        accgp += cf * seedF[row * CC + lane];
        if (lane == 0) {
            conf[row] = cf;
            sg[row] = sigmoidf(8.f * (cf - 0.55f));
            accconf += cf;
        }
    }
    __shared__ float sgp[256];
    __shared__ float scf[4];
    sgp[threadIdx.x] = accgp;
    if (lane == 0) scf[wid] = accconf;
    __syncthreads();
    if (threadIdx.x < 64)
        atomicAdd(&gp[lane], sgp[lane] + sgp[64 + lane] + sgp[128 + lane] + sgp[192 + lane]);
    if (threadIdx.x == 0) atomicAdd(&scal[2], scf[0] + scf[1] + scf[2] + scf[3]);
}

__global__ void k_finalize(float* __restrict__ scal, float* __restrict__ gp) {
    float sc = fmaxf(scal[2], EPSF);
    gp[threadIdx.x] = gp[threadIdx.x] / sc;
    if (threadIdx.x == 0) {
        scal[3] = fminf(fmaxf(1.f - scal[1] * (1.f / NN), 0.2f), 1.f);
    }
}

// ---------------- CSR build: hist + scan + direct scatter ----------------

__global__ void k_hist(const int* __restrict__ dst, int* __restrict__ count, int E) {
    int i = blockIdx.x * blockDim.x + threadIdx.x;
    int stride = gridDim.x * blockDim.x;
    for (; i < E; i += stride) atomicAdd(&count[dst[i]], 1);
}

__global__ void k_bsum(const int* __restrict__ count, int* __restrict__ bsum) {
    int b = blockIdx.x, t = threadIdx.x;
    int base = b * SCAN_BS + t * 4;
    int s = 0;
#pragma unroll
    for (int k = 0; k < 4; ++k) {
        int i = base + k;
        if (i < NN) s += count[i];
    }
#pragma unroll
    for (int off = 32; off; off >>= 1) s += __shfl_xor(s, off);
    __shared__ int red[4];
    if ((t & 63) == 0) red[t >> 6] = s;
    __syncthreads();
    if (t == 0) bsum[b] = red[0] + red[1] + red[2] + red[3];
}

__global__ void k_boff(const int* __restrict__ bsum, int* __restrict__ boff,
                       int* __restrict__ row_start) {
    int acc = 0;
    for (int i = 0; i < NSB; ++i) { boff[i] = acc; acc += bsum[i]; }
    row_start[NN] = acc;  // == E
}

__global__ void k_scanwrite(const int* __restrict__ count, const int* __restrict__ boff,
                            int* __restrict__ row_start, int* __restrict__ cursor) {
    int b = blockIdx.x, t = threadIdx.x, lane = t & 63, wid = t >> 6;
    int base = b * SCAN_BS + t * 4;
    int c0 = 0, c1 = 0, c2 = 0, c3 = 0;
    if (base < NN) c0 = count[base];
    if (base + 1 < NN) c1 = count[base + 1];
    if (base + 2 < NN) c2 = count[base + 2];
    if (base + 3 < NN) c3 = count[base + 3];
    int s = c0 + c1 + c2 + c3;
    int incl = s;
#pragma unroll
    for (int off = 1; off < 64; off <<= 1) {
        int o = __shfl_up(incl, off);
        if (lane >= off) incl += o;
    }
    __shared__ int wsum[4];
    if (lane == 63) wsum[wid] = incl;
    __syncthreads();
    int woff = 0;
    for (int i = 0; i < wid; ++i) woff += wsum[i];
    int excl = boff[b] + woff + incl - s;
    if (base < NN) { row_start[base] = excl; cursor[base] = excl; excl += c0; }
    if (base + 1 < NN) { row_start[base + 1] = excl; cursor[base + 1] = excl; excl += c1; }
    if (base + 2 < NN) { row_start[base + 2] = excl; cursor[base + 2] = excl; excl += c2; }
    if (base + 3 < NN) { row_start[base + 3] = excl; cursor[base + 3] = excl; excl += c3; }
}

// Direct per-row scatter (measured 130-140 µs; beats binned variants).
__global__ void k_scatter(const int* __restrict__ src, const int* __restrict__ dst,
                          const float* __restrict__ w, int* __restrict__ cursor,
                          int2* __restrict__ edge_pk, int E) {
    int i = blockIdx.x * blockDim.x + threadIdx.x;
    int stride = gridDim.x * blockDim.x;
    for (; i < E; i += stride) {
        int d = dst[i];
        int pos = atomicAdd(&cursor[d], 1);
        edge_pk[pos] = make_int2(src[i], __float_as_int(w[i]));
    }
}

// ---------------- fused CSR gather (bf16) + update, one wave per row -------
// Lane layout: g = lane>>3 (edge slot 0..7), c = lane&7 (channel octet).
// Gathered state xH is bf16 (128 B/row). fp32 masters: seedF, gp.
// MODE 0: ctx=sum w*seed[s]; num=sum (w*sg)*seed[s]; den; base quality -> bq;
//         fused step-0 update -> poutH (bf16).
// MODE 1: num = sum (w*sg[s])*x[s]; fused update -> poutH.
// MODE 2: ctx = sum w*x[s]; quality + accept vs bq + blend with seedF -> outF.

template <int MODE>
__global__ __launch_bounds__(256) void k_csr(
    const int2* __restrict__ edge_pk, const int* __restrict__ row_start,
    const ushortT* __restrict__ xH, const float* __restrict__ sg,
    const float* __restrict__ seedF, const float* __restrict__ sf,
    const float* __restrict__ conf, const float* __restrict__ gp,
    const float* __restrict__ scal, float* __restrict__ den,
    float* __restrict__ bq, ushortT* __restrict__ poutH,
    float* __restrict__ outF) {
    int lane = threadIdx.x & 63;
    int row = blockIdx.x * 4 + (threadIdx.x >> 6);
    if (row >= NN) return;
    int g = lane >> 3, c = lane & 7;
    int rs = row_start[row], re = row_start[row + 1];

    float acc[8], accn[8];
    float accden = 0.f;
#pragma unroll
    for (int i = 0; i < 8; ++i) { acc[i] = 0.f; accn[i] = 0.f; }

    for (int base = rs; base < re; base += 16) {
        int e0 = base + g;
        int e1 = base + 8 + g;
        int2 pk0 = make_int2(0, 0), pk1 = make_int2(0, 0);
        if (e0 < re) pk0 = edge_pk[e0];
        if (e1 < re) pk1 = edge_pk[e1];
        float w0 = __int_as_float(pk0.y);
        float w1 = __int_as_float(pk1.y);
        const uint4 v0 = *(const uint4*)(xH + (size_t)pk0.x * CC + c * 8);
        const uint4 v1 = *(const uint4*)(xH + (size_t)pk1.x * CC + c * 8);
        float x0[8], x1[8];
        unpack8(v0, x0);
        unpack8(v1, x1);
        float wa0 = w0, wa1 = w1;
        if (MODE == 1) { wa0 = w0 * sg[pk0.x]; wa1 = w1 * sg[pk1.x]; }
#pragma unroll
        for (int i = 0; i < 8; ++i) acc[i] += wa0 * x0[i] + wa1 * x1[i];
        if (MODE == 0) {
            float ws0 = w0 * sg[pk0.x];
            float ws1 = w1 * sg[pk1.x];
#pragma unroll
            for (int i = 0; i < 8; ++i) accn[i] += ws0 * x0[i] + ws1 * x1[i];
            accden += ws0 + ws1;
        }
    }

#pragma unroll
    for (int i = 0; i < 8; ++i) acc[i] = redGSum(acc[i]);

    if (MODE == 1) {
        float dn = fmaxf(den[row], EPSF);
        float inv = 1.f / dn;
        float p[8], s[8], g8[8], f[8];
        uint4 pv = *(const uint4*)(xH + (size_t)row * CC + c * 8);
        unpack8(pv, p);
        const float4 sa = *(const float4*)(seedF + (size_t)row * CC + c * 8);
        const float4 sb = *(const float4*)(seedF + (size_t)row * CC + c * 8 + 4);
        s[0] = sa.x; s[1] = sa.y; s[2] = sa.z; s[3] = sa.w;
        s[4] = sb.x; s[5] = sb.y; s[6] = sb.z; s[7] = sb.w;
        const float4 ga = *(const float4*)(gp + c * 8);
        const float4 gb = *(const float4*)(gp + c * 8 + 4);
        g8[0] = ga.x; g8[1] = ga.y; g8[2] = ga.z; g8[3] = ga.w;
        g8[4] = gb.x; g8[5] = gb.y; g8[6] = gb.z; g8[7] = gb.w;
        float pf = 0.f, pp = 0.f, ff = 0.f, sfv = 0.f, ss = 0.f;
#pragma unroll
        for (int i = 0; i < 8; ++i) {
            f[i] = 0.95f * (acc[i] * inv) + 0.05f * g8[i];
            pf += p[i] * f[i]; pp += p[i] * p[i]; ff += f[i] * f[i];
            sfv += s[i] * f[i]; ss += s[i] * s[i];
        }
        pf = redCSum(pf); pp = redCSum(pp); ff = redCSum(ff);
        sfv = redCSum(sfv); ss = redCSum(ss);
        float nf = fmaxf(sqrtf(ff), 1e-8f);
        float agree = clip01((pf / (fmaxf(sqrtf(pp), 1e-8f) * nf) + 1.f) * 0.5f);
        float sagree = clip01((sfv / (fmaxf(sqrtf(ss), 1e-8f) * nf) + 1.f) * 0.5f);
        float cf = conf[row];
        float anchor = fminf(fmaxf(0.6f + 0.2f * cf, 0.f), 0.995f);
        float lowdeg = clip01(1.f - sf[row * 2 + 0]);
        float lowcl = clip01(1.f - sf[row * 2 + 1]);
        float rec = sigmoidf(8.f * (0.5f - cf));
        float sel = clip01((1.f - cf) + 0.25f * lowdeg + 0.2f * sagree + 0.2f * lowcl);
        float ug = rec * sel * agree * (1.f - anchor);
        float rsc = 0.15f * scal[3] * ug;
        if (g == 0) {
            float o[8];
#pragma unroll
            for (int i = 0; i < 8; ++i)
                o[i] = fmaxf(anchor * s[i] + (1.f - anchor) * p[i] + rsc * (f[i] - p[i]), 0.f);
            *(uint4*)(poutH + (size_t)row * CC + c * 8) = pack8(o);
        }
        return;
    }

    // MODE 0 / MODE 2: quality epilogue. s = seed row (fp32) or prop row (bf16).
    float s[8];
    if (MODE == 0) {
        const float4 sa = *(const float4*)(seedF + (size_t)row * CC + c * 8);
        const float4 sb = *(const float4*)(seedF + (size_t)row * CC + c * 8 + 4);
        s[0] = sa.x; s[1] = sa.y; s[2] = sa.z; s[3] = sa.w;
        s[4] = sb.x; s[5] = sb.y; s[6] = sb.z; s[7] = sb.w;
    } else {
        uint4 pv = *(const uint4*)(xH + (size_t)row * CC + c * 8);
        unpack8(pv, s);
    }
    float dot = 0.f, ss = 0.f, cc2 = 0.f, m = 0.f;
#pragma unroll
    for (int i = 0; i < 8; ++i) {
        dot += s[i] * acc[i]; ss += s[i] * s[i]; cc2 += acc[i] * acc[i]; m += s[i];
    }
    dot = redCSum(dot); ss = redCSum(ss); cc2 = redCSum(cc2); m = redCSum(m);
    float cosv = dot / (fmaxf(sqrtf(ss), 1e-8f) * fmaxf(sqrtf(cc2), 1e-8f));
    float lq = clip01((cosv + 1.f) * 0.5f);
    float minv = 1.f / (m + EPSF);
    float lmax = -3.4e38f;
#pragma unroll
    for (int i = 0; i < 8; ++i) lmax = fmaxf(lmax, s[i] * minv);
    float m1 = redCMax(lmax);
    float cnt = 0.f, mlt = -3.4e38f;
#pragma unroll
    for (int i = 0; i < 8; ++i) {
        float p = s[i] * minv;
        cnt += (p == m1) ? 1.f : 0.f;
        mlt = fmaxf(mlt, (p < m1) ? p : -3.4e38f);
    }
    cnt = redCSum(cnt);
    mlt = redCMax(mlt);
    float m2 = (cnt >= 2.f) ? m1 : mlt;
    float q = 0.7f * lq + 0.2f * (m1 - m2) + 0.1f * sf[row * 2 + 1];

    if (MODE == 0) {
#pragma unroll
        for (int i = 0; i < 8; ++i) accn[i] = redGSum(accn[i]);
        accden = redGSum(accden);
        float dn = fmaxf(accden, EPSF);
        float inv = 1.f / dn;
        float g8[8], f[8];
        const float4 ga = *(const float4*)(gp + c * 8);
        const float4 gb = *(const float4*)(gp + c * 8 + 4);
        g8[0] = ga.x; g8[1] = ga.y; g8[2] = ga.z; g8[3] = ga.w;
        g8[4] = gb.x; g8[5] = gb.y; g8[6] = gb.z; g8[7] = gb.w;
        float sfv = 0.f, ff = 0.f;
#pragma unroll
        for (int i = 0; i < 8; ++i) {
            f[i] = 0.95f * (accn[i] * inv) + 0.05f * g8[i];
            sfv += s[i] * f[i]; ff += f[i] * f[i];
        }
        sfv = redCSum(sfv); ff = redCSum(ff);
        float nf = fmaxf(sqrtf(ff), 1e-8f);
        float sagree = clip01((sfv / (fmaxf(sqrtf(ss), 1e-8f) * nf) + 1.f) * 0.5f);
        float cf = conf[row];
        float anchor = fminf(fmaxf(0.6f + 0.2f * cf, 0.f), 0.995f);
        float lowdeg = clip01(1.f - sf[row * 2 + 0]);
        float lowcl = clip01(1.f - sf[row * 2 + 1]);
        float rec = sigmoidf(8.f * (0.5f - cf));
        float sel = clip01((1.f - cf) + 0.25f * lowdeg + 0.2f * sagree + 0.2f * lowcl);
        float ug = rec * sel * sagree * (1.f - anchor);
        float rsc = 0.15f * scal[3] * ug;
        if (g == 0) {
            float o[8];
#pragma unroll
            for (int i = 0; i < 8; ++i) o[i] = fmaxf(s[i] + rsc * (f[i] - s[i]), 0.f);
            *(uint4*)(poutH + (size_t)row * CC + c * 8) = pack8(o);
        }
        if (lane == 0) {
            den[row] = accden;
            bq[row] = q;
        }
    } else {  // MODE 2: accept + blend -> fp32 out
        float accp = sigmoidf(12.f * (q - bq[row]));
        const float4 sa = *(const float4*)(seedF + (size_t)row * CC + c * 8);
        const float4 sb = *(const float4*)(seedF + (size_t)row * CC + c * 8 + 4);
        float sd[8] = {sa.x, sa.y, sa.z, sa.w, sb.x, sb.y, sb.z, sb.w};
        if (g == 0) {
            float4 o1, o2;
            o1.x = accp * s[0] + (1.f - accp) * sd[0];
            o1.y = accp * s[1] + (1.f - accp) * sd[1];
            o1.z = accp * s[2] + (1.f - accp) * sd[2];
            o1.w = accp * s[3] + (1.f - accp) * sd[3];
            o2.x = accp * s[4] + (1.f - accp) * sd[4];
            o2.y = accp * s[5] + (1.f - accp) * sd[5];
            o2.z = accp * s[6] + (1.f - accp) * sd[6];
            o2.w = accp * s[7] + (1.f - accp) * sd[7];
            *(float4*)(outF + (size_t)row * CC + c * 8) = o1;
            *(float4*)(outF + (size_t)row * CC + c * 8 + 4) = o2;
        }
    }
}

// ---------------- launcher ----------------

extern "C" void kernel_launch(void* const* d_in, const int* in_sizes, int n_in,
                              void* d_out, int out_size, void* d_ws, size_t ws_size,
                              hipStream_t stream) {
    const float* logits = (const float*)d_in[0];
    const float* ew = (const float*)d_in[1];
    const float* sf = (const float*)d_in[2];
    const int* esrc = (const int*)d_in[3];
    const int* edst = (const int*)d_in[4];
    float* out = (float*)d_out;
    int E = in_sizes[1];

    float* ws = (float*)d_ws;
    float* seedF = ws;                             // N*C fp32   (25.6 MB)
    ushortT* seedH = (ushortT*)(seedF + NN * CC);  // N*C bf16   (12.8 MB)
    ushortT* propAH = seedH + NN * CC;             // N*C bf16   (12.8 MB)
    int2* edge_pk = (int2*)(propAH + NN * CC);     // E int2     (12.8 MB) 8B-aligned
    float* fb = (float*)(edge_pk + E);
    float* massA = fb;                             // N
    float* certA = massA + NN;                     // N
    float* confA = certA + NN;                     // N
    float* sgA = confA + NN;                       // N
    float* denA = sgA + NN;                        // N
    float* bqA = denA + NN;                        // N
    float* scal = bqA + NN;                        // 16
    float* gp = scal + 16;                         // 64
    int* count = (int*)(gp + 64);                  // N
    int* cursor = count + NN;                      // N
    int* row_start = cursor + NN;                  // N+1
    int* bsum = row_start + NN + 1;                // NSB
    int* boff = bsum + NSB;                        // NSB
    ushortT* propBH = (ushortT*)d_out;             // lives in d_out; dead before final write

    hipMemsetAsync(scal, 0, 16 * sizeof(float), stream);
    hipMemsetAsync(count, 0, NN * sizeof(int), stream);

    const int redBlocks = 1024;
    const int rowBlocks = (NN + 3) / 4;
    const int edgeBlocks = 1024;

    k_seed<<<redBlocks, 256, 0, stream>>>(logits, sf, seedF, seedH, massA, certA, scal);
    k_conf<<<redBlocks, 256, 0, stream>>>(seedF, massA, certA, confA, sgA, scal, gp);
    k_finalize<<<1, 64, 0, stream>>>(scal, gp);

    k_hist<<<edgeBlocks, 256, 0, stream>>>(edst, count, E);
    k_bsum<<<NSB, 256, 0, stream>>>(count, bsum);
    k_boff<<<1, 1, 0, stream>>>(bsum, boff, row_start);
    k_scanwrite<<<NSB, 256, 0, stream>>>(count, boff, row_start, cursor);
    k_scatter<<<edgeBlocks, 256, 0, stream>>>(esrc, edst, ew, cursor, edge_pk, E);

    // base pass: ctx(seed) quality + den + fused step-0 update -> propAH
    k_csr<0><<<rowBlocks, 256, 0, stream>>>(edge_pk, row_start, seedH, sgA, seedF, sf,
                                            confA, gp, scal, denA, bqA, propAH, nullptr);
    // steps 1,2: gather + fused update, ping-pong propAH <-> propBH(d_out)
    k_csr<1><<<rowBlocks, 256, 0, stream>>>(edge_pk, row_start, propAH, sgA, seedF, sf,
                                            confA, gp, scal, denA, bqA, propBH, nullptr);
    k_csr<1><<<rowBlocks, 256, 0, stream>>>(edge_pk, row_start, propBH, sgA, seedF, sf,
                                            confA, gp, scal, denA, bqA, propAH, nullptr);
    // final: ctx(propAH) + quality + accept + blend -> fp32 out (overwrites dead propBH)
    k_csr<2><<<rowBlocks, 256, 0, stream>>>(edge_pk, row_start, propAH, sgA, seedF, sf,
                                            confA, gp, scal, denA, bqA, nullptr, out);
}

// Round 11
// 528.084 us; speedup vs baseline: 1.4510x; 1.1025x over previous
//
#include <hip/hip_runtime.h>
#include <math.h>

#define NN 100000
#define CC 64
#define EPSF 1e-8f
#define LOG_C 4.1588830833596715f
#define SCAN_BS 1024
#define NSB ((NN + SCAN_BS - 1) / SCAN_BS)
#define NREG ((NN + 1023) >> 10)     // 98 regions of 1024 rows
#define RBLK 256                     // producer blocks for the counting sort

typedef unsigned short ushortT;
typedef unsigned int uintT;

__device__ __forceinline__ float waveSum(float v) {
#pragma unroll
    for (int off = 32; off; off >>= 1) v += __shfl_xor(v, off);
    return v;
}
// reduce across the 8 channel-lanes (bits 0..2)
__device__ __forceinline__ float redCSum(float v) {
    v += __shfl_xor(v, 1); v += __shfl_xor(v, 2); v += __shfl_xor(v, 4);
    return v;
}
__device__ __forceinline__ float redCMax(float v) {
    v = fmaxf(v, __shfl_xor(v, 1)); v = fmaxf(v, __shfl_xor(v, 2)); v = fmaxf(v, __shfl_xor(v, 4));
    return v;
}
// reduce across the 8 edge-groups (bits 3..5)
__device__ __forceinline__ float redGSum(float v) {
    v += __shfl_xor(v, 8); v += __shfl_xor(v, 16); v += __shfl_xor(v, 32);
    return v;
}
__device__ __forceinline__ float clip01(float v) { return fminf(fmaxf(v, 0.f), 1.f); }
__device__ __forceinline__ float sigmoidf(float x) { return 1.f / (1.f + expf(-x)); }

__device__ __forceinline__ void unpack8(const uint4 v, float* x) {
    x[0] = __uint_as_float(v.x << 16); x[1] = __uint_as_float(v.x & 0xFFFF0000u);
    x[2] = __uint_as_float(v.y << 16); x[3] = __uint_as_float(v.y & 0xFFFF0000u);
    x[4] = __uint_as_float(v.z << 16); x[5] = __uint_as_float(v.z & 0xFFFF0000u);
    x[6] = __uint_as_float(v.w << 16); x[7] = __uint_as_float(v.w & 0xFFFF0000u);
}
__device__ __forceinline__ uintT f2bf(float f) {  // RNE round to bf16 (low 16 bits)
    uintT u = __float_as_uint(f);
    return (u + 0x7FFFu + ((u >> 16) & 1u)) >> 16;
}
__device__ __forceinline__ uint4 pack8(const float* x) {
    uint4 o;
    o.x = f2bf(x[0]) | (f2bf(x[1]) << 16);
    o.y = f2bf(x[2]) | (f2bf(x[3]) << 16);
    o.z = f2bf(x[4]) | (f2bf(x[5]) << 16);
    o.w = f2bf(x[6]) | (f2bf(x[7]) << 16);
    return o;
}

// ---------------- row-wise prologue ----------------

__global__ void k_seed(const float* __restrict__ logits, const float* __restrict__ sf,
                       float* __restrict__ seedF, ushortT* __restrict__ seedH,
                       float* __restrict__ mass, float* __restrict__ cert,
                       float* __restrict__ scal) {
    int lane = threadIdx.x & 63;
    int wid = threadIdx.x >> 6;
    float accm = 0.f, accc = 0.f;
    for (int row = blockIdx.x * 4 + wid; row < NN; row += gridDim.x * 4) {
        float l = logits[row * CC + lane];
        float s = fmaxf(l, 0.f);
        seedF[row * CC + lane] = s;
        seedH[row * CC + lane] = (ushortT)f2bf(s);
        float m = waveSum(s);
        float nrm = s / (m + EPSF);
        float ent = waveSum(-nrm * logf(nrm + EPSF));
        if (lane == 0) {
            mass[row] = m;
            cert[row] = 1.f - ent / LOG_C;
            accm += m;
            accc += sf[row * 2 + 1];
        }
    }
    __shared__ float sm[8];
    if (lane == 0) { sm[wid] = accm; sm[4 + wid] = accc; }
    __syncthreads();
    if (threadIdx.x == 0) {
        atomicAdd(&scal[0], sm[0] + sm[1] + sm[2] + sm[3]);
        atomicAdd(&scal[1], sm[4] + sm[5] + sm[6] + sm[7]);
    }
}

__global__ void k_conf(const float* __restrict__ seedF, const float* __restrict__ mass,
                       const float* __restrict__ cert, float* __restrict__ conf,
                       float* __restrict__ sg, float* __restrict__ scal,
                       float* __restrict__ gp) {
    int lane = threadIdx.x & 63;
    int wid = threadIdx.x >> 6;
    float msc = fmaxf(scal[0] * (1.f / NN), EPSF);
    float accgp = 0.f, accconf = 0.f;
    for (int row = blockIdx.x * 4 + wid; row < NN; row += gridDim.x * 4) {
        float m = mass[row], ct = cert[row];
        float cf = clip01(0.5f * ct + 0.5f * tanhf(m / msc));
        accgp += cf * seedF[row * CC + lane];
        if (lane == 0) {
            conf[row] = cf;
            sg[row] = sigmoidf(8.f * (cf - 0.55f));
            accconf += cf;
        }
    }
    __shared__ float sgp[256];
    __shared__ float scf[4];
    sgp[threadIdx.x] = accgp;
    if (lane == 0) scf[wid] = accconf;
    __syncthreads();
    if (threadIdx.x < 64)
        atomicAdd(&gp[lane], sgp[lane] + sgp[64 + lane] + sgp[128 + lane] + sgp[192 + lane]);
    if (threadIdx.x == 0) atomicAdd(&scal[2], scf[0] + scf[1] + scf[2] + scf[3]);
}

__global__ void k_finalize(float* __restrict__ scal, float* __restrict__ gp) {
    float sc = fmaxf(scal[2], EPSF);
    gp[threadIdx.x] = gp[threadIdx.x] / sc;
    if (threadIdx.x == 0) {
        scal[3] = fminf(fmaxf(1.f - scal[1] * (1.f / NN), 0.2f), 1.f);
    }
}

// ---------------- CSR build: row hist + row scan ----------------

__global__ void k_hist(const int* __restrict__ dst, int* __restrict__ count, int E) {
    int i = blockIdx.x * blockDim.x + threadIdx.x;
    int stride = gridDim.x * blockDim.x;
    for (; i < E; i += stride) atomicAdd(&count[dst[i]], 1);
}

__global__ void k_bsum(const int* __restrict__ count, int* __restrict__ bsum) {
    int b = blockIdx.x, t = threadIdx.x;
    int base = b * SCAN_BS + t * 4;
    int s = 0;
#pragma unroll
    for (int k = 0; k < 4; ++k) {
        int i = base + k;
        if (i < NN) s += count[i];
    }
#pragma unroll
    for (int off = 32; off; off >>= 1) s += __shfl_xor(s, off);
    __shared__ int red[4];
    if ((t & 63) == 0) red[t >> 6] = s;
    __syncthreads();
    if (t == 0) bsum[b] = red[0] + red[1] + red[2] + red[3];
}

__global__ void k_boff(const int* __restrict__ bsum, int* __restrict__ boff,
                       int* __restrict__ row_start) {
    int acc = 0;
    for (int i = 0; i < NSB; ++i) { boff[i] = acc; acc += bsum[i]; }
    row_start[NN] = acc;  // == E
}

__global__ void k_scanwrite(const int* __restrict__ count, const int* __restrict__ boff,
                            int* __restrict__ row_start, int* __restrict__ cursor) {
    int b = blockIdx.x, t = threadIdx.x, lane = t & 63, wid = t >> 6;
    int base = b * SCAN_BS + t * 4;
    int c0 = 0, c1 = 0, c2 = 0, c3 = 0;
    if (base < NN) c0 = count[base];
    if (base + 1 < NN) c1 = count[base + 1];
    if (base + 2 < NN) c2 = count[base + 2];
    if (base + 3 < NN) c3 = count[base + 3];
    int s = c0 + c1 + c2 + c3;
    int incl = s;
#pragma unroll
    for (int off = 1; off < 64; off <<= 1) {
        int o = __shfl_up(incl, off);
        if (lane >= off) incl += o;
    }
    __shared__ int wsum[4];
    if (lane == 63) wsum[wid] = incl;
    __syncthreads();
    int woff = 0;
    for (int i = 0; i < wid; ++i) woff += wsum[i];
    int excl = boff[b] + woff + incl - s;
    if (base < NN) { row_start[base] = excl; cursor[base] = excl; excl += c0; }
    if (base + 1 < NN) { row_start[base + 1] = excl; cursor[base + 1] = excl; excl += c1; }
    if (base + 2 < NN) { row_start[base + 2] = excl; cursor[base + 2] = excl; excl += c2; }
    if (base + 3 < NN) { row_start[base + 3] = excl; cursor[base + 3] = excl; excl += c3; }
}

// ---------------- atomic-free-offset counting sort (region = 1024 rows) ----
// Record: (src | dst_low10<<17, w) — src < 2^17, dst_low < 1024.

// Phase A: per-(producer block, region) counts via private LDS histogram.
__global__ __launch_bounds__(256) void k_rcount(const int* __restrict__ dst,
                                                int* __restrict__ cnts, int E) {
    __shared__ int h[NREG];
    for (int i = threadIdx.x; i < NREG; i += 256) h[i] = 0;
    __syncthreads();
    int per = (E + RBLK - 1) / RBLK;
    int b0 = blockIdx.x * per;
    int b1 = min(b0 + per, E);
    for (int e = b0 + threadIdx.x; e < b1; e += 256)
        atomicAdd(&h[dst[e] >> 10], 1);
    __syncthreads();
    for (int r = threadIdx.x; r < NREG; r += 256)
        cnts[r * RBLK + blockIdx.x] = h[r];
}

// Phase B: exclusive scan of cnts (r-major, b-minor). Single 1024-thread block.
// Cumulative totals over regions 0..r-1 equal row_start[r*1024] by construction.
__global__ __launch_bounds__(1024) void k_rscan(const int* __restrict__ cnts,
                                                int* __restrict__ offs) {
    const int TOT = NREG * RBLK;       // 25088
    const int PER = (TOT + 1023) / 1024;  // 25
    int t = threadIdx.x, lane = t & 63, wid = t >> 6;
    int base = t * PER;
    int loc[PER];
    int s = 0;
#pragma unroll
    for (int k = 0; k < PER; ++k) {
        int i = base + k;
        int v = (i < TOT) ? cnts[i] : 0;
        loc[k] = s;
        s += v;
    }
    int incl = s;
#pragma unroll
    for (int off = 1; off < 64; off <<= 1) {
        int o = __shfl_up(incl, off);
        if (lane >= off) incl += o;
    }
    __shared__ int wsum[16];
    if (lane == 63) wsum[wid] = incl;
    __syncthreads();
    int woff = 0;
    for (int i = 0; i < wid; ++i) woff += wsum[i];
    int excl = woff + incl - s;
#pragma unroll
    for (int k = 0; k < PER; ++k) {
        int i = base + k;
        if (i < TOT) offs[i] = excl + loc[k];
    }
}

// Phase C: place records at block-private frontiers (LDS cursors, dense writes,
// zero inter-block frontier sharing, no syncthreads in the stream loop).
__global__ __launch_bounds__(256) void k_rbin(const int* __restrict__ src,
                                              const int* __restrict__ dst,
                                              const float* __restrict__ w,
                                              const int* __restrict__ offs,
                                              int2* __restrict__ tmp_pk, int E) {
    __shared__ int cur[NREG];
    for (int r = threadIdx.x; r < NREG; r += 256)
        cur[r] = offs[r * RBLK + blockIdx.x];
    __syncthreads();
    int per = (E + RBLK - 1) / RBLK;
    int b0 = blockIdx.x * per;
    int b1 = min(b0 + per, E);
    for (int e = b0 + threadIdx.x; e < b1; e += 256) {
        int d = dst[e];
        int r = d >> 10;
        int pos = atomicAdd(&cur[r], 1);
        tmp_pk[pos] = make_int2(src[e] | ((d & 1023) << 17), __float_as_int(w[e]));
    }
}

// Phase D: one block per region permutes its contiguous slice to exact row
// positions — window is single-XCD-local, L2 merges the write-backs.
__global__ __launch_bounds__(256) void k_runbin(const int* __restrict__ row_start,
                                                const int2* __restrict__ tmp_pk,
                                                int2* __restrict__ edge_pk) {
    __shared__ int cur[1024];
    int r0 = blockIdx.x << 10;
    int r1 = min(r0 + 1024, NN);
    for (int i = threadIdx.x; i < r1 - r0; i += 256) cur[i] = row_start[r0 + i];
    __syncthreads();
    int s = row_start[r0], e = row_start[r1];
    for (int i = s + threadIdx.x; i < e; i += 256) {
        int2 t = tmp_pk[i];
        int dl = (t.x >> 17) & 1023;
        int pos = atomicAdd(&cur[dl], 1);
        edge_pk[pos] = make_int2(t.x & 0x1FFFF, t.y);
    }
}

// Fallback (ws too small): proven direct per-row scatter.
__global__ void k_scatter(const int* __restrict__ src, const int* __restrict__ dst,
                          const float* __restrict__ w, int* __restrict__ cursor,
                          int2* __restrict__ edge_pk, int E) {
    int i = blockIdx.x * blockDim.x + threadIdx.x;
    int stride = gridDim.x * blockDim.x;
    for (; i < E; i += stride) {
        int d = dst[i];
        int pos = atomicAdd(&cursor[d], 1);
        edge_pk[pos] = make_int2(src[i], __float_as_int(w[i]));
    }
}

// ---------------- fused CSR gather (bf16) + update, one wave per row -------
// Lane layout: g = lane>>3 (edge slot 0..7), c = lane&7 (channel octet).
// MODE 0: ctx=sum w*seed[s]; num=sum (w*sg)*seed[s]; den; base quality -> bq;
//         fused step-0 update -> poutH (bf16).
// MODE 1: num = sum (w*sg[s])*x[s]; fused update -> poutH.
// MODE 2: ctx = sum w*x[s]; quality + accept vs bq + blend with seedF -> outF.

template <int MODE>
__global__ __launch_bounds__(256) void k_csr(
    const int2* __restrict__ edge_pk, const int* __restrict__ row_start,
    const ushortT* __restrict__ xH, const float* __restrict__ sg,
    const float* __restrict__ seedF, const float* __restrict__ sf,
    const float* __restrict__ conf, const float* __restrict__ gp,
    const float* __restrict__ scal, float* __restrict__ den,
    float* __restrict__ bq, ushortT* __restrict__ poutH,
    float* __restrict__ outF) {
    int lane = threadIdx.x & 63;
    int row = blockIdx.x * 4 + (threadIdx.x >> 6);
    if (row >= NN) return;
    int g = lane >> 3, c = lane & 7;
    int rs = row_start[row], re = row_start[row + 1];

    float acc[8], accn[8];
    float accden = 0.f;
#pragma unroll
    for (int i = 0; i < 8; ++i) { acc[i] = 0.f; accn[i] = 0.f; }

    for (int base = rs; base < re; base += 16) {
        int e0 = base + g;
        int e1 = base + 8 + g;
        int2 pk0 = make_int2(0, 0), pk1 = make_int2(0, 0);
        if (e0 < re) pk0 = edge_pk[e0];
        if (e1 < re) pk1 = edge_pk[e1];
        float w0 = __int_as_float(pk0.y);
        float w1 = __int_as_float(pk1.y);
        const uint4 v0 = *(const uint4*)(xH + (size_t)pk0.x * CC + c * 8);
        const uint4 v1 = *(const uint4*)(xH + (size_t)pk1.x * CC + c * 8);
        float x0[8], x1[8];
        unpack8(v0, x0);
        unpack8(v1, x1);
        float wa0 = w0, wa1 = w1;
        if (MODE == 1) { wa0 = w0 * sg[pk0.x]; wa1 = w1 * sg[pk1.x]; }
#pragma unroll
        for (int i = 0; i < 8; ++i) acc[i] += wa0 * x0[i] + wa1 * x1[i];
        if (MODE == 0) {
            float ws0 = w0 * sg[pk0.x];
            float ws1 = w1 * sg[pk1.x];
#pragma unroll
            for (int i = 0; i < 8; ++i) accn[i] += ws0 * x0[i] + ws1 * x1[i];
            accden += ws0 + ws1;
        }
    }

#pragma unroll
    for (int i = 0; i < 8; ++i) acc[i] = redGSum(acc[i]);

    if (MODE == 1) {
        float dn = fmaxf(den[row], EPSF);
        float inv = 1.f / dn;
        float p[8], s[8], g8[8], f[8];
        uint4 pv = *(const uint4*)(xH + (size_t)row * CC + c * 8);
        unpack8(pv, p);
        const float4 sa = *(const float4*)(seedF + (size_t)row * CC + c * 8);
        const float4 sb = *(const float4*)(seedF + (size_t)row * CC + c * 8 + 4);
        s[0] = sa.x; s[1] = sa.y; s[2] = sa.z; s[3] = sa.w;
        s[4] = sb.x; s[5] = sb.y; s[6] = sb.z; s[7] = sb.w;
        const float4 ga = *(const float4*)(gp + c * 8);
        const float4 gb = *(const float4*)(gp + c * 8 + 4);
        g8[0] = ga.x; g8[1] = ga.y; g8[2] = ga.z; g8[3] = ga.w;
        g8[4] = gb.x; g8[5] = gb.y; g8[6] = gb.z; g8[7] = gb.w;
        float pf = 0.f, pp = 0.f, ff = 0.f, sfv = 0.f, ss = 0.f;
#pragma unroll
        for (int i = 0; i < 8; ++i) {
            f[i] = 0.95f * (acc[i] * inv) + 0.05f * g8[i];
            pf += p[i] * f[i]; pp += p[i] * p[i]; ff += f[i] * f[i];
            sfv += s[i] * f[i]; ss += s[i] * s[i];
        }
        pf = redCSum(pf); pp = redCSum(pp); ff = redCSum(ff);
        sfv = redCSum(sfv); ss = redCSum(ss);
        float nf = fmaxf(sqrtf(ff), 1e-8f);
        float agree = clip01((pf / (fmaxf(sqrtf(pp), 1e-8f) * nf) + 1.f) * 0.5f);
        float sagree = clip01((sfv / (fmaxf(sqrtf(ss), 1e-8f) * nf) + 1.f) * 0.5f);
        float cf = conf[row];
        float anchor = fminf(fmaxf(0.6f + 0.2f * cf, 0.f), 0.995f);
        float lowdeg = clip01(1.f - sf[row * 2 + 0]);
        float lowcl = clip01(1.f - sf[row * 2 + 1]);
        float rec = sigmoidf(8.f * (0.5f - cf));
        float sel = clip01((1.f - cf) + 0.25f * lowdeg + 0.2f * sagree + 0.2f * lowcl);
        float ug = rec * sel * agree * (1.f - anchor);
        float rsc = 0.15f * scal[3] * ug;
        if (g == 0) {
            float o[8];
#pragma unroll
            for (int i = 0; i < 8; ++i)
                o[i] = fmaxf(anchor * s[i] + (1.f - anchor) * p[i] + rsc * (f[i] - p[i]), 0.f);
            *(uint4*)(poutH + (size_t)row * CC + c * 8) = pack8(o);
        }
        return;
    }

    // MODE 0 / MODE 2: quality epilogue. s = seed row (fp32) or prop row (bf16).
    float s[8];
    if (MODE == 0) {
        const float4 sa = *(const float4*)(seedF + (size_t)row * CC + c * 8);
        const float4 sb = *(const float4*)(seedF + (size_t)row * CC + c * 8 + 4);
        s[0] = sa.x; s[1] = sa.y; s[2] = sa.z; s[3] = sa.w;
        s[4] = sb.x; s[5] = sb.y; s[6] = sb.z; s[7] = sb.w;
    } else {
        uint4 pv = *(const uint4*)(xH + (size_t)row * CC + c * 8);
        unpack8(pv, s);
    }
    float dot = 0.f, ss = 0.f, cc2 = 0.f, m = 0.f;
#pragma unroll
    for (int i = 0; i < 8; ++i) {
        dot += s[i] * acc[i]; ss += s[i] * s[i]; cc2 += acc[i] * acc[i]; m += s[i];
    }
    dot = redCSum(dot); ss = redCSum(ss); cc2 = redCSum(cc2); m = redCSum(m);
    float cosv = dot / (fmaxf(sqrtf(ss), 1e-8f) * fmaxf(sqrtf(cc2), 1e-8f));
    float lq = clip01((cosv + 1.f) * 0.5f);
    float minv = 1.f / (m + EPSF);
    float lmax = -3.4e38f;
#pragma unroll
    for (int i = 0; i < 8; ++i) lmax = fmaxf(lmax, s[i] * minv);
    float m1 = redCMax(lmax);
    float cnt = 0.f, mlt = -3.4e38f;
#pragma unroll
    for (int i = 0; i < 8; ++i) {
        float p = s[i] * minv;
        cnt += (p == m1) ? 1.f : 0.f;
        mlt = fmaxf(mlt, (p < m1) ? p : -3.4e38f);
    }
    cnt = redCSum(cnt);
    mlt = redCMax(mlt);
    float m2 = (cnt >= 2.f) ? m1 : mlt;
    float q = 0.7f * lq + 0.2f * (m1 - m2) + 0.1f * sf[row * 2 + 1];

    if (MODE == 0) {
#pragma unroll
        for (int i = 0; i < 8; ++i) accn[i] = redGSum(accn[i]);
        accden = redGSum(accden);
        float dn = fmaxf(accden, EPSF);
        float inv = 1.f / dn;
        float g8[8], f[8];
        const float4 ga = *(const float4*)(gp + c * 8);
        const float4 gb = *(const float4*)(gp + c * 8 + 4);
        g8[0] = ga.x; g8[1] = ga.y; g8[2] = ga.z; g8[3] = ga.w;
        g8[4] = gb.x; g8[5] = gb.y; g8[6] = gb.z; g8[7] = gb.w;
        float sfv = 0.f, ff = 0.f;
#pragma unroll
        for (int i = 0; i < 8; ++i) {
            f[i] = 0.95f * (accn[i] * inv) + 0.05f * g8[i];
            sfv += s[i] * f[i]; ff += f[i] * f[i];
        }
        sfv = redCSum(sfv); ff = redCSum(ff);
        float nf = fmaxf(sqrtf(ff), 1e-8f);
        float sagree = clip01((sfv / (fmaxf(sqrtf(ss), 1e-8f) * nf) + 1.f) * 0.5f);
        float cf = conf[row];
        float anchor = fminf(fmaxf(0.6f + 0.2f * cf, 0.f), 0.995f);
        float lowdeg = clip01(1.f - sf[row * 2 + 0]);
        float lowcl = clip01(1.f - sf[row * 2 + 1]);
        float rec = sigmoidf(8.f * (0.5f - cf));
        float sel = clip01((1.f - cf) + 0.25f * lowdeg + 0.2f * sagree + 0.2f * lowcl);
        float ug = rec * sel * sagree * (1.f - anchor);
        float rsc = 0.15f * scal[3] * ug;
        if (g == 0) {
            float o[8];
#pragma unroll
            for (int i = 0; i < 8; ++i) o[i] = fmaxf(s[i] + rsc * (f[i] - s[i]), 0.f);
            *(uint4*)(poutH + (size_t)row * CC + c * 8) = pack8(o);
        }
        if (lane == 0) {
            den[row] = accden;
            bq[row] = q;
        }
    } else {  // MODE 2: accept + blend -> fp32 out
        float accp = sigmoidf(12.f * (q - bq[row]));
        const float4 sa = *(const float4*)(seedF + (size_t)row * CC + c * 8);
        const float4 sb = *(const float4*)(seedF + (size_t)row * CC + c * 8 + 4);
        float sd[8] = {sa.x, sa.y, sa.z, sa.w, sb.x, sb.y, sb.z, sb.w};
        if (g == 0) {
            float4 o1, o2;
            o1.x = accp * s[0] + (1.f - accp) * sd[0];
            o1.y = accp * s[1] + (1.f - accp) * sd[1];
            o1.z = accp * s[2] + (1.f - accp) * sd[2];
            o1.w = accp * s[3] + (1.f - accp) * sd[3];
            o2.x = accp * s[4] + (1.f - accp) * sd[4];
            o2.y = accp * s[5] + (1.f - accp) * sd[5];
            o2.z = accp * s[6] + (1.f - accp) * sd[6];
            o2.w = accp * s[7] + (1.f - accp) * sd[7];
            *(float4*)(outF + (size_t)row * CC + c * 8) = o1;
            *(float4*)(outF + (size_t)row * CC + c * 8 + 4) = o2;
        }
    }
}

// ---------------- launcher ----------------

extern "C" void kernel_launch(void* const* d_in, const int* in_sizes, int n_in,
                              void* d_out, int out_size, void* d_ws, size_t ws_size,
                              hipStream_t stream) {
    const float* logits = (const float*)d_in[0];
    const float* ew = (const float*)d_in[1];
    const float* sf = (const float*)d_in[2];
    const int* esrc = (const int*)d_in[3];
    const int* edst = (const int*)d_in[4];
    float* out = (float*)d_out;
    int E = in_sizes[1];

    float* ws = (float*)d_ws;
    float* seedF = ws;                             // N*C fp32   (25.6 MB)
    ushortT* seedH = (ushortT*)(seedF + NN * CC);  // N*C bf16   (12.8 MB)
    ushortT* propAH = seedH + NN * CC;             // N*C bf16   (12.8 MB)
    int2* edge_pk = (int2*)(propAH + NN * CC);     // E int2     (12.8 MB)
    int2* tmp_pk = edge_pk + E;                    // E int2     (12.8 MB)
    float* fb = (float*)(tmp_pk + E);
    float* massA = fb;                             // N
    float* certA = massA + NN;                     // N
    float* confA = certA + NN;                     // N
    float* sgA = confA + NN;                       // N
    float* denA = sgA + NN;                        // N
    float* bqA = denA + NN;                        // N
    float* scal = bqA + NN;                        // 16
    float* gp = scal + 16;                         // 64
    int* count = (int*)(gp + 64);                  // N
    int* cursor = count + NN;                      // N
    int* row_start = cursor + NN;                  // N+1
    int* bsum = row_start + NN + 1;                // NSB
    int* boff = bsum + NSB;                        // NSB
    int* cnts = boff + NSB;                        // NREG*RBLK
    int* offs = cnts + NREG * RBLK;                // NREG*RBLK
    ushortT* propBH = (ushortT*)d_out;             // dead before final write

    size_t need_bytes = (size_t)((char*)(offs + NREG * RBLK) - (char*)ws);
    bool sort_path = ws_size >= need_bytes;

    hipMemsetAsync(scal, 0, 16 * sizeof(float), stream);
    hipMemsetAsync(count, 0, NN * sizeof(int), stream);

    const int redBlocks = 1024;
    const int rowBlocks = (NN + 3) / 4;
    const int edgeBlocks = 1024;

    k_seed<<<redBlocks, 256, 0, stream>>>(logits, sf, seedF, seedH, massA, certA, scal);
    k_conf<<<redBlocks, 256, 0, stream>>>(seedF, massA, certA, confA, sgA, scal, gp);
    k_finalize<<<1, 64, 0, stream>>>(scal, gp);

    k_hist<<<edgeBlocks, 256, 0, stream>>>(edst, count, E);
    k_bsum<<<NSB, 256, 0, stream>>>(count, bsum);
    k_boff<<<1, 1, 0, stream>>>(bsum, boff, row_start);
    k_scanwrite<<<NSB, 256, 0, stream>>>(count, boff, row_start, cursor);

    if (sort_path) {
        k_rcount<<<RBLK, 256, 0, stream>>>(edst, cnts, E);
        k_rscan<<<1, 1024, 0, stream>>>(cnts, offs);
        k_rbin<<<RBLK, 256, 0, stream>>>(esrc, edst, ew, offs, tmp_pk, E);
        k_runbin<<<NREG, 256, 0, stream>>>(row_start, tmp_pk, edge_pk);
    } else {
        k_scatter<<<edgeBlocks, 256, 0, stream>>>(esrc, edst, ew, cursor, edge_pk, E);
    }

    // base pass: ctx(seed) quality + den + fused step-0 update -> propAH
    k_csr<0><<<rowBlocks, 256, 0, stream>>>(edge_pk, row_start, seedH, sgA, seedF, sf,
                                            confA, gp, scal, denA, bqA, propAH, nullptr);
    // steps 1,2: gather + fused update, ping-pong propAH <-> propBH(d_out)
    k_csr<1><<<rowBlocks, 256, 0, stream>>>(edge_pk, row_start, propAH, sgA, seedF, sf,
                                            confA, gp, scal, denA, bqA, propBH, nullptr);
    k_csr<1><<<rowBlocks, 256, 0, stream>>>(edge_pk, row_start, propBH, sgA, seedF, sf,
                                            confA, gp, scal, denA, bqA, propAH, nullptr);
    // final: ctx(propAH) + quality + accept + blend -> fp32 out (overwrites dead propBH)
    k_csr<2><<<rowBlocks, 256, 0, stream>>>(edge_pk, row_start, propAH, sgA, seedF, sf,
                                            confA, gp, scal, denA, bqA, nullptr, out);
}